// Round 1
// baseline (339.824 us; speedup 1.0000x reference)
//
#include <hip/hip_runtime.h>
#include <hip/hip_bf16.h>

typedef unsigned short u16;
typedef unsigned int u32;
typedef __attribute__((ext_vector_type(8))) __bf16 bf16x8;
typedef __attribute__((ext_vector_type(4))) float f32x4;

// f32 -> bf16 round-to-nearest-even
__device__ __forceinline__ u16 f2bf(float f) {
  u32 u = __builtin_bit_cast(u32, f);
  return (u16)((u + 0x7fffu + ((u >> 16) & 1u)) >> 16);
}

// ---------------- cast x: fp32 -> bf16, 8 elems/thread ----------------
__global__ __launch_bounds__(256) void cast_x_kernel(const float* __restrict__ x,
                                                     u16* __restrict__ xb) {
  size_t i = ((size_t)blockIdx.x * 256 + threadIdx.x) * 8;
  float4 a = *(const float4*)(x + i);
  float4 b = *(const float4*)(x + i + 4);
  union { u16 h[8]; uint4 v; } o;
  o.h[0] = f2bf(a.x); o.h[1] = f2bf(a.y); o.h[2] = f2bf(a.z); o.h[3] = f2bf(a.w);
  o.h[4] = f2bf(b.x); o.h[5] = f2bf(b.y); o.h[6] = f2bf(b.z); o.h[7] = f2bf(b.w);
  *(uint4*)(xb + i) = o.v;
}

// ---------- cast + transpose W: [2048][256] f32 -> Wbt[768][2048] bf16 ----------
// grid (E/32=64, D/32=8, 3), block (32,8)
__global__ void cast_w_kernel(const float* __restrict__ Wq, const float* __restrict__ Wk,
                              const float* __restrict__ Wv, u16* __restrict__ wbt) {
  __shared__ float tile[32][33];
  int e0 = blockIdx.x * 32, d0 = blockIdx.y * 32, w = blockIdx.z;
  const float* W = (w == 0) ? Wq : ((w == 1) ? Wk : Wv);
  int x = threadIdx.x, y = threadIdx.y;
#pragma unroll
  for (int j = 0; j < 4; j++)
    tile[y + j * 8][x] = W[(size_t)(e0 + y + j * 8) * 256 + d0 + x];
  __syncthreads();
#pragma unroll
  for (int j = 0; j < 4; j++)
    wbt[(size_t)(w * 256 + d0 + y + j * 8) * 2048 + e0 + x] = f2bf(tile[x][y + j * 8]);
}

// ---------------- GEMM: qkv[16384][768] = xb[16384][2048] * Wbt^T ----------------
// m97 structure: 128x128 tile, BK=64, 4 waves, global_load_lds, 2-barrier loop.
// grid (128, 6), block 256
__global__ __launch_bounds__(256) void gemm_kernel(const u16* __restrict__ A,
                                                   const u16* __restrict__ Bt,
                                                   u16* __restrict__ C) {
  __shared__ __align__(16) u16 As[128 * 64];
  __shared__ __align__(16) u16 Bs[128 * 64];
  int tid = threadIdx.x;
  int w = tid >> 6, l = tid & 63;
  int lr = l & 15, lg = l >> 4;
  int row0 = blockIdx.x * 128, col0 = blockIdx.y * 128;
  int wr = w >> 1, wc = w & 1;

  f32x4 acc[4][4];
#pragma unroll
  for (int m = 0; m < 4; m++)
#pragma unroll
    for (int n = 0; n < 4; n++) acc[m][n] = (f32x4){0.f, 0.f, 0.f, 0.f};

  // staging coords: wave w covers rows w*32 + j*8 + (l>>3), cols (l&7)*8 of the tile
  const u16* ga = A + (size_t)(row0 + w * 32 + (l >> 3)) * 2048 + (l & 7) * 8;
  const u16* gb = Bt + (size_t)(col0 + w * 32 + (l >> 3)) * 2048 + (l & 7) * 8;

  for (int kt = 0; kt < 2048; kt += 64) {
    __syncthreads();  // previous compute done reading LDS
#pragma unroll
    for (int j = 0; j < 4; j++) {
      __builtin_amdgcn_global_load_lds(
          (const __attribute__((address_space(1))) void*)(ga + kt + (size_t)j * 8 * 2048),
          (__attribute__((address_space(3))) void*)&As[w * 2048 + j * 512], 16, 0, 0);
      __builtin_amdgcn_global_load_lds(
          (const __attribute__((address_space(1))) void*)(gb + kt + (size_t)j * 8 * 2048),
          (__attribute__((address_space(3))) void*)&Bs[w * 2048 + j * 512], 16, 0, 0);
    }
    __syncthreads();  // loads drained (vmcnt(0) implicit before barrier)
#pragma unroll
    for (int kk = 0; kk < 64; kk += 32) {
      bf16x8 af[4], bfr[4];
#pragma unroll
      for (int m = 0; m < 4; m++)
        af[m] = *(const bf16x8*)&As[(wr * 64 + m * 16 + lr) * 64 + kk + lg * 8];
#pragma unroll
      for (int n = 0; n < 4; n++)
        bfr[n] = *(const bf16x8*)&Bs[(wc * 64 + n * 16 + lr) * 64 + kk + lg * 8];
#pragma unroll
      for (int m = 0; m < 4; m++)
#pragma unroll
        for (int n = 0; n < 4; n++)
          acc[m][n] = __builtin_amdgcn_mfma_f32_16x16x32_bf16(af[m], bfr[n], acc[m][n], 0, 0, 0);
    }
  }
  // C write: row = (l>>4)*4 + i, col = l&15 within each 16x16 frag
  int crow = row0 + wr * 64;
  int ccol = col0 + wc * 64 + lr;
#pragma unroll
  for (int m = 0; m < 4; m++)
#pragma unroll
    for (int n = 0; n < 4; n++)
#pragma unroll
      for (int i = 0; i < 4; i++)
        C[(size_t)(crow + m * 16 + lg * 4 + i) * 768 + ccol + n * 16] = f2bf(acc[m][n][i]);
}

// ---------------- V transpose: qkv[...][512+d] -> vt[b][d][t] ----------------
// grid (T/32=64, D/32=8, B=8), block (32,8)
__global__ void vtrans_kernel(const u16* __restrict__ qkv, u16* __restrict__ vt) {
  __shared__ u16 tile[32][33];
  int t0 = blockIdx.x * 32, d0 = blockIdx.y * 32, b = blockIdx.z;
  int x = threadIdx.x, y = threadIdx.y;
#pragma unroll
  for (int j = 0; j < 4; j++)
    tile[y + j * 8][x] = qkv[(size_t)(b * 2048 + t0 + y + j * 8) * 768 + 512 + d0 + x];
  __syncthreads();
#pragma unroll
  for (int j = 0; j < 4; j++)
    vt[(size_t)b * 524288 + (size_t)(d0 + y + j * 8) * 2048 + t0 + x] = tile[x][y + j * 8];
}

// ---------------- flash attention, causal, logits = S/256 ----------------
// grid (T/16=128, B=8), block 256 (4 waves). Each block: 16 q rows.
// Waves split KV blocks (32 wide) stride-4; LSE merge at the end through LDS.
__global__ __launch_bounds__(256) void attn_kernel(const u16* __restrict__ qkv,
                                                   const u16* __restrict__ vt,
                                                   float* __restrict__ out) {
  __shared__ float sacc[4][16][260];
  __shared__ float sm[4][16];
  __shared__ float sl[4][16];
  __shared__ __align__(16) u16 plds[4][16][40];

  int tid = threadIdx.x;
  int w = tid >> 6, l = tid & 63;
  int lr = l & 15, lg = l >> 4;
  int q0 = blockIdx.x * 16, b = blockIdx.y;

  // Q fragments hoisted: lane holds Q[q0+lr][kc*32 + lg*8 + 0..7]
  const u16* qrow = qkv + (size_t)(b * 2048 + q0 + lr) * 768;
  bf16x8 qa[8];
#pragma unroll
  for (int kc = 0; kc < 8; kc++)
    qa[kc] = *(const bf16x8*)(qrow + kc * 32 + lg * 8);

  f32x4 o[16];
#pragma unroll
  for (int n = 0; n < 16; n++) o[n] = (f32x4){0.f, 0.f, 0.f, 0.f};
  float mreg[4] = {-__builtin_inff(), -__builtin_inff(), -__builtin_inff(), -__builtin_inff()};
  float ell[4] = {0.f, 0.f, 0.f, 0.f};

  const u16* kbase = qkv + (size_t)b * 2048 * 768 + 256;
  const u16* vbase = vt + (size_t)b * 524288;
  int nkv = (q0 >> 5) + 1;

  for (int jb = w; jb < nkv; jb += 4) {
    int kv0 = jb * 32;
    f32x4 s0 = (f32x4){0.f, 0.f, 0.f, 0.f}, s1 = s0;
    const u16* krow0 = kbase + (size_t)(kv0 + lr) * 768 + lg * 8;
#pragma unroll
    for (int kc = 0; kc < 8; kc++) {
      bf16x8 kf = *(const bf16x8*)(krow0 + kc * 32);
      s0 = __builtin_amdgcn_mfma_f32_16x16x32_bf16(qa[kc], kf, s0, 0, 0, 0);
    }
    const u16* krow1 = krow0 + 16 * 768;
#pragma unroll
    for (int kc = 0; kc < 8; kc++) {
      bf16x8 kf = *(const bf16x8*)(krow1 + kc * 32);
      s1 = __builtin_amdgcn_mfma_f32_16x16x32_bf16(qa[kc], kf, s1, 0, 0, 0);
    }
    // mask + net 1/D scale
    float sv0[4], sv1[4];
#pragma unroll
    for (int i = 0; i < 4; i++) {
      int qg = q0 + lg * 4 + i;
      sv0[i] = (kv0 + lr <= qg) ? s0[i] * (1.0f / 256.0f) : -__builtin_inff();
      sv1[i] = (kv0 + 16 + lr <= qg) ? s1[i] * (1.0f / 256.0f) : -__builtin_inff();
    }
    // online softmax, wave-parallel 16-lane reductions
    float sfv[4];
#pragma unroll
    for (int i = 0; i < 4; i++) {
      float mx = fmaxf(sv0[i], sv1[i]);
      mx = fmaxf(mx, __shfl_xor(mx, 1));
      mx = fmaxf(mx, __shfl_xor(mx, 2));
      mx = fmaxf(mx, __shfl_xor(mx, 4));
      mx = fmaxf(mx, __shfl_xor(mx, 8));
      float mnew = fmaxf(mreg[i], mx);
      float sf = __expf(mreg[i] - mnew);
      float p0 = __expf(sv0[i] - mnew);
      float p1 = __expf(sv1[i] - mnew);
      plds[w][lg * 4 + i][lr] = f2bf(p0);
      plds[w][lg * 4 + i][16 + lr] = f2bf(p1);
      float ps = p0 + p1;
      ps += __shfl_xor(ps, 1);
      ps += __shfl_xor(ps, 2);
      ps += __shfl_xor(ps, 4);
      ps += __shfl_xor(ps, 8);
      ell[i] = ell[i] * sf + ps;
      mreg[i] = mnew;
      sfv[i] = sf;
    }
#pragma unroll
    for (int n = 0; n < 16; n++) {
      f32x4 t = o[n];
      t[0] *= sfv[0]; t[1] *= sfv[1]; t[2] *= sfv[2]; t[3] *= sfv[3];
      o[n] = t;
    }
    // P as A-fragment: lane holds P[lr][lg*8 + 0..7]
    bf16x8 pa = *(const bf16x8*)&plds[w][lr][lg * 8];
    const u16* vrow = vbase + (size_t)lr * 2048 + kv0 + lg * 8;
#pragma unroll
    for (int n = 0; n < 16; n++) {
      bf16x8 vf = *(const bf16x8*)(vrow + (size_t)n * 16 * 2048);
      o[n] = __builtin_amdgcn_mfma_f32_16x16x32_bf16(pa, vf, o[n], 0, 0, 0);
    }
  }

  // publish per-wave state
#pragma unroll
  for (int i = 0; i < 4; i++) {
    if (lr == i) {
      sm[w][lg * 4 + i] = mreg[i];
      sl[w][lg * 4 + i] = ell[i];
    }
  }
#pragma unroll
  for (int n = 0; n < 16; n++)
#pragma unroll
    for (int i = 0; i < 4; i++)
      sacc[w][lg * 4 + i][n * 16 + lr] = o[n][i];
  __syncthreads();

  // LSE merge across the 4 waves; thread -> (row, d-lane) with stride-16 d
  int r = tid >> 4, dl = tid & 15;
  float m0 = sm[0][r], m1 = sm[1][r], m2 = sm[2][r], m3 = sm[3][r];
  float M = fmaxf(fmaxf(m0, m1), fmaxf(m2, m3));
  float a0 = __expf(m0 - M), a1 = __expf(m1 - M), a2 = __expf(m2 - M), a3 = __expf(m3 - M);
  float denom = a0 * sl[0][r] + a1 * sl[1][r] + a2 * sl[2][r] + a3 * sl[3][r];
  float inv = 1.0f / denom;
  float* orow = out + (size_t)(b * 2048 + q0 + r) * 256;
#pragma unroll
  for (int j = 0; j < 16; j++) {
    int d = dl + j * 16;
    float v = a0 * sacc[0][r][d] + a1 * sacc[1][r][d] + a2 * sacc[2][r][d] + a3 * sacc[3][r][d];
    orow[d] = v * inv;
  }
}

extern "C" void kernel_launch(void* const* d_in, const int* in_sizes, int n_in,
                              void* d_out, int out_size, void* d_ws, size_t ws_size,
                              hipStream_t stream) {
  (void)in_sizes; (void)n_in; (void)out_size; (void)ws_size;
  const float* x = (const float*)d_in[0];
  const float* Wq = (const float*)d_in[1];
  const float* Wk = (const float*)d_in[2];
  const float* Wv = (const float*)d_in[3];
  float* out = (float*)d_out;

  char* ws = (char*)d_ws;
  u16* xb  = (u16*)(ws);                    // 16384*2048*2   = 67,108,864 B
  u16* wbt = (u16*)(ws + 67108864);         // 768*2048*2     =  3,145,728 B
  u16* qkv = (u16*)(ws + 70254592);         // 16384*768*2    = 25,165,824 B
  u16* vt  = (u16*)(ws + 95420416);         // 8*256*2048*2   =  8,388,608 B
                                            // total 103,809,024 B

  cast_x_kernel<<<16384, 256, 0, stream>>>(x, xb);
  cast_w_kernel<<<dim3(64, 8, 3), dim3(32, 8), 0, stream>>>(Wq, Wk, Wv, wbt);
  gemm_kernel<<<dim3(128, 6), 256, 0, stream>>>(xb, wbt, qkv);
  vtrans_kernel<<<dim3(64, 8, 8), dim3(32, 8), 0, stream>>>(qkv, vt);
  attn_kernel<<<dim3(128, 8), 256, 0, stream>>>(qkv, vt, out);
}

// Round 2
// 325.016 us; speedup vs baseline: 1.0456x; 1.0456x over previous
//
#include <hip/hip_runtime.h>
#include <hip/hip_bf16.h>

typedef unsigned short u16;
typedef unsigned int u32;
typedef __attribute__((ext_vector_type(8))) __bf16 bf16x8;
typedef __attribute__((ext_vector_type(4))) float f32x4;

// f32 -> bf16 round-to-nearest-even
__device__ __forceinline__ u16 f2bf(float f) {
  u32 u = __builtin_bit_cast(u32, f);
  return (u16)((u + 0x7fffu + ((u >> 16) & 1u)) >> 16);
}

// ---------------- cast x: fp32 -> bf16, 8 elems/thread ----------------
__global__ __launch_bounds__(256) void cast_x_kernel(const float* __restrict__ x,
                                                     u16* __restrict__ xb) {
  size_t i = ((size_t)blockIdx.x * 256 + threadIdx.x) * 8;
  float4 a = *(const float4*)(x + i);
  float4 b = *(const float4*)(x + i + 4);
  union { u16 h[8]; uint4 v; } o;
  o.h[0] = f2bf(a.x); o.h[1] = f2bf(a.y); o.h[2] = f2bf(a.z); o.h[3] = f2bf(a.w);
  o.h[4] = f2bf(b.x); o.h[5] = f2bf(b.y); o.h[6] = f2bf(b.z); o.h[7] = f2bf(b.w);
  *(uint4*)(xb + i) = o.v;
}

// ---------- cast + transpose W: [2048][256] f32 -> Wbt[768][2048] bf16 ----------
__global__ void cast_w_kernel(const float* __restrict__ Wq, const float* __restrict__ Wk,
                              const float* __restrict__ Wv, u16* __restrict__ wbt) {
  __shared__ float tile[32][33];
  int e0 = blockIdx.x * 32, d0 = blockIdx.y * 32, w = blockIdx.z;
  const float* W = (w == 0) ? Wq : ((w == 1) ? Wk : Wv);
  int x = threadIdx.x, y = threadIdx.y;
#pragma unroll
  for (int j = 0; j < 4; j++)
    tile[y + j * 8][x] = W[(size_t)(e0 + y + j * 8) * 256 + d0 + x];
  __syncthreads();
#pragma unroll
  for (int j = 0; j < 4; j++)
    wbt[(size_t)(w * 256 + d0 + y + j * 8) * 2048 + e0 + x] = f2bf(tile[x][y + j * 8]);
}

// ---------------- GEMM: qkv[16384][768] = xb[16384][2048] * Wbt^T ----------------
__global__ __launch_bounds__(256) void gemm_kernel(const u16* __restrict__ A,
                                                   const u16* __restrict__ Bt,
                                                   u16* __restrict__ C) {
  __shared__ __align__(16) u16 As[128 * 64];
  __shared__ __align__(16) u16 Bs[128 * 64];
  int tid = threadIdx.x;
  int w = tid >> 6, l = tid & 63;
  int lr = l & 15, lg = l >> 4;
  int row0 = blockIdx.x * 128, col0 = blockIdx.y * 128;
  int wr = w >> 1, wc = w & 1;

  f32x4 acc[4][4];
#pragma unroll
  for (int m = 0; m < 4; m++)
#pragma unroll
    for (int n = 0; n < 4; n++) acc[m][n] = (f32x4){0.f, 0.f, 0.f, 0.f};

  const u16* ga = A + (size_t)(row0 + w * 32 + (l >> 3)) * 2048 + (l & 7) * 8;
  const u16* gb = Bt + (size_t)(col0 + w * 32 + (l >> 3)) * 2048 + (l & 7) * 8;

  for (int kt = 0; kt < 2048; kt += 64) {
    __syncthreads();
#pragma unroll
    for (int j = 0; j < 4; j++) {
      __builtin_amdgcn_global_load_lds(
          (const __attribute__((address_space(1))) void*)(ga + kt + (size_t)j * 8 * 2048),
          (__attribute__((address_space(3))) void*)&As[w * 2048 + j * 512], 16, 0, 0);
      __builtin_amdgcn_global_load_lds(
          (const __attribute__((address_space(1))) void*)(gb + kt + (size_t)j * 8 * 2048),
          (__attribute__((address_space(3))) void*)&Bs[w * 2048 + j * 512], 16, 0, 0);
    }
    __syncthreads();
#pragma unroll
    for (int kk = 0; kk < 64; kk += 32) {
      bf16x8 af[4], bfr[4];
#pragma unroll
      for (int m = 0; m < 4; m++)
        af[m] = *(const bf16x8*)&As[(wr * 64 + m * 16 + lr) * 64 + kk + lg * 8];
#pragma unroll
      for (int n = 0; n < 4; n++)
        bfr[n] = *(const bf16x8*)&Bs[(wc * 64 + n * 16 + lr) * 64 + kk + lg * 8];
#pragma unroll
      for (int m = 0; m < 4; m++)
#pragma unroll
        for (int n = 0; n < 4; n++)
          acc[m][n] = __builtin_amdgcn_mfma_f32_16x16x32_bf16(af[m], bfr[n], acc[m][n], 0, 0, 0);
    }
  }
  int crow = row0 + wr * 64;
  int ccol = col0 + wc * 64 + lr;
#pragma unroll
  for (int m = 0; m < 4; m++)
#pragma unroll
    for (int n = 0; n < 4; n++)
#pragma unroll
      for (int i = 0; i < 4; i++)
        C[(size_t)(crow + m * 16 + lg * 4 + i) * 768 + ccol + n * 16] = f2bf(acc[m][n][i]);
}

// ---------------- V transpose: qkv[...][512+d] -> vt[b][d][t] ----------------
__global__ void vtrans_kernel(const u16* __restrict__ qkv, u16* __restrict__ vt) {
  __shared__ u16 tile[32][33];
  int t0 = blockIdx.x * 32, d0 = blockIdx.y * 32, b = blockIdx.z;
  int x = threadIdx.x, y = threadIdx.y;
#pragma unroll
  for (int j = 0; j < 4; j++)
    tile[y + j * 8][x] = qkv[(size_t)(b * 2048 + t0 + y + j * 8) * 768 + 512 + d0 + x];
  __syncthreads();
#pragma unroll
  for (int j = 0; j < 4; j++)
    vt[(size_t)b * 524288 + (size_t)(d0 + y + j * 8) * 2048 + t0 + x] = tile[x][y + j * 8];
}

// ---------------- flash attention v2: causal, logits = S/256 ----------------
// grid (64, 8), block 256 (4 waves). Block handles 32 q rows (jt = 63-bx, q0=jt*32).
// ALL 4 waves own the SAME 32 q rows; they split KV blocks (32 wide) stride-4.
// Each wave: acc o[2][16] (32q x 256d), Q frags hoisted (2x8), K/V read from L2.
// Merge: sequential fp32 add into facc (34 KB) + LSE via sm/sl.
__global__ __launch_bounds__(256, 2) void attn_kernel(const u16* __restrict__ qkv,
                                                      const u16* __restrict__ vt,
                                                      float* __restrict__ out) {
  __shared__ float facc[32][268];
  __shared__ float sm[4][32];
  __shared__ float sl[4][32];
  __shared__ __align__(16) u16 plds[4][32][40];

  int tid = threadIdx.x;
  int w = tid >> 6, l = tid & 63;
  int lr = l & 15, lg = l >> 4;
  int jt = 63 - blockIdx.x;  // big causal tiles first (balance heuristic)
  int b = blockIdx.y;
  int q0 = jt * 32;

  // Q fragments hoisted: qa[qr][kc] = Q[q0+qr*16+lr][kc*32+lg*8 .. +7]
  const u16* qbase = qkv + (size_t)(b * 2048 + q0) * 768;
  bf16x8 qa[2][8];
#pragma unroll
  for (int qr = 0; qr < 2; qr++)
#pragma unroll
    for (int kc = 0; kc < 8; kc++)
      qa[qr][kc] = *(const bf16x8*)(qbase + (size_t)(qr * 16 + lr) * 768 + kc * 32 + lg * 8);

  f32x4 o[2][16];
#pragma unroll
  for (int qr = 0; qr < 2; qr++)
#pragma unroll
    for (int n = 0; n < 16; n++) o[qr][n] = (f32x4){0.f, 0.f, 0.f, 0.f};
  float mreg[2][4], ell[2][4];
#pragma unroll
  for (int qr = 0; qr < 2; qr++)
#pragma unroll
    for (int i = 0; i < 4; i++) { mreg[qr][i] = -__builtin_inff(); ell[qr][i] = 0.f; }

  const u16* kbase = qkv + (size_t)b * 2048 * 768 + 256;
  const u16* vbase = vt + (size_t)b * 524288;
  int nkv = jt + 1;

  for (int jb = w; jb < nkv; jb += 4) {
    int kv0 = jb * 32;
    f32x4 s[2][2];
    s[0][0] = (f32x4){0.f,0.f,0.f,0.f}; s[0][1] = s[0][0];
    s[1][0] = s[0][0]; s[1][1] = s[0][0];
    const u16* kr = kbase + (size_t)(kv0 + lr) * 768 + lg * 8;
#pragma unroll
    for (int h = 0; h < 2; h++)
#pragma unroll
      for (int kc = 0; kc < 8; kc++) {
        bf16x8 kf = *(const bf16x8*)(kr + (size_t)h * 16 * 768 + kc * 32);
        s[0][h] = __builtin_amdgcn_mfma_f32_16x16x32_bf16(qa[0][kc], kf, s[0][h], 0, 0, 0);
        s[1][h] = __builtin_amdgcn_mfma_f32_16x16x32_bf16(qa[1][kc], kf, s[1][h], 0, 0, 0);
      }

    // mask (diagonal tile only) + net 1/D scale
    float sv[2][2][4];
    if (jb == jt) {
#pragma unroll
      for (int qr = 0; qr < 2; qr++)
#pragma unroll
        for (int h = 0; h < 2; h++)
#pragma unroll
          for (int i = 0; i < 4; i++) {
            int qrow = qr * 16 + lg * 4 + i;
            int krow = h * 16 + lr;
            sv[qr][h][i] = (krow <= qrow) ? s[qr][h][i] * (1.0f / 256.0f) : -__builtin_inff();
          }
    } else {
#pragma unroll
      for (int qr = 0; qr < 2; qr++)
#pragma unroll
        for (int h = 0; h < 2; h++)
#pragma unroll
          for (int i = 0; i < 4; i++)
            sv[qr][h][i] = s[qr][h][i] * (1.0f / 256.0f);
    }

    // online softmax, wave-parallel 16-lane reductions
    float sfv[2][4];
#pragma unroll
    for (int qr = 0; qr < 2; qr++)
#pragma unroll
      for (int i = 0; i < 4; i++) {
        float v0 = sv[qr][0][i], v1 = sv[qr][1][i];
        float mx = fmaxf(v0, v1);
        mx = fmaxf(mx, __shfl_xor(mx, 1));
        mx = fmaxf(mx, __shfl_xor(mx, 2));
        mx = fmaxf(mx, __shfl_xor(mx, 4));
        mx = fmaxf(mx, __shfl_xor(mx, 8));
        float mnew = fmaxf(mreg[qr][i], mx);
        float sf = __expf(mreg[qr][i] - mnew);
        float p0 = __expf(v0 - mnew);
        float p1 = __expf(v1 - mnew);
        plds[w][qr * 16 + lg * 4 + i][lr] = f2bf(p0);
        plds[w][qr * 16 + lg * 4 + i][16 + lr] = f2bf(p1);
        float ps = p0 + p1;
        ps += __shfl_xor(ps, 1);
        ps += __shfl_xor(ps, 2);
        ps += __shfl_xor(ps, 4);
        ps += __shfl_xor(ps, 8);
        ell[qr][i] = ell[qr][i] * sf + ps;
        mreg[qr][i] = mnew;
        sfv[qr][i] = sf;
      }

    // rescale accumulators
#pragma unroll
    for (int qr = 0; qr < 2; qr++)
#pragma unroll
      for (int n = 0; n < 16; n++) {
        f32x4 t = o[qr][n];
        t[0] *= sfv[qr][0]; t[1] *= sfv[qr][1]; t[2] *= sfv[qr][2]; t[3] *= sfv[qr][3];
        o[qr][n] = t;
      }

    // PV: P as A-fragment, V^T frags from global (L2-resident)
    bf16x8 pa0 = *(const bf16x8*)&plds[w][lr][lg * 8];
    bf16x8 pa1 = *(const bf16x8*)&plds[w][16 + lr][lg * 8];
    const u16* vr = vbase + (size_t)lr * 2048 + kv0 + lg * 8;
#pragma unroll
    for (int n = 0; n < 16; n++) {
      bf16x8 vf = *(const bf16x8*)(vr + (size_t)n * 16 * 2048);
      o[0][n] = __builtin_amdgcn_mfma_f32_16x16x32_bf16(pa0, vf, o[0][n], 0, 0, 0);
      o[1][n] = __builtin_amdgcn_mfma_f32_16x16x32_bf16(pa1, vf, o[1][n], 0, 0, 0);
    }
  }

  // publish per-wave m, l
  if (lr == 0) {
#pragma unroll
    for (int qr = 0; qr < 2; qr++)
#pragma unroll
      for (int i = 0; i < 4; i++) {
        sm[w][qr * 16 + lg * 4 + i] = mreg[qr][i];
        sl[w][qr * 16 + lg * 4 + i] = ell[qr][i];
      }
  }
  __syncthreads();

  // per-wave alpha for its rows
  float alpha[2][4];
#pragma unroll
  for (int qr = 0; qr < 2; qr++)
#pragma unroll
    for (int i = 0; i < 4; i++) {
      int r = qr * 16 + lg * 4 + i;
      float M = fmaxf(fmaxf(sm[0][r], sm[1][r]), fmaxf(sm[2][r], sm[3][r]));
      alpha[qr][i] = __expf(mreg[qr][i] - M);
    }

  // sequential scaled accumulate into facc
#pragma unroll
  for (int ww = 0; ww < 4; ww++) {
    if (w == ww) {
#pragma unroll
      for (int qr = 0; qr < 2; qr++)
#pragma unroll
        for (int n = 0; n < 16; n++)
#pragma unroll
          for (int i = 0; i < 4; i++) {
            int r = qr * 16 + lg * 4 + i;
            float v = alpha[qr][i] * o[qr][n][i];
            if (ww == 0) facc[r][n * 16 + lr] = v;
            else facc[r][n * 16 + lr] += v;
          }
    }
    __syncthreads();
  }

  // final: row r = tid>>3, 32 floats per thread, float4 stores
  int r = tid >> 3, c0 = (tid & 7) * 32;
  float M = fmaxf(fmaxf(sm[0][r], sm[1][r]), fmaxf(sm[2][r], sm[3][r]));
  float denom = __expf(sm[0][r] - M) * sl[0][r] + __expf(sm[1][r] - M) * sl[1][r] +
                __expf(sm[2][r] - M) * sl[2][r] + __expf(sm[3][r] - M) * sl[3][r];
  float inv = 1.0f / denom;
  float* orow = out + (size_t)(b * 2048 + q0 + r) * 256;
#pragma unroll
  for (int j = 0; j < 8; j++) {
    float4 v = *(const float4*)&facc[r][c0 + j * 4];
    v.x *= inv; v.y *= inv; v.z *= inv; v.w *= inv;
    *(float4*)&orow[c0 + j * 4] = v;
  }
}

extern "C" void kernel_launch(void* const* d_in, const int* in_sizes, int n_in,
                              void* d_out, int out_size, void* d_ws, size_t ws_size,
                              hipStream_t stream) {
  (void)in_sizes; (void)n_in; (void)out_size; (void)ws_size;
  const float* x = (const float*)d_in[0];
  const float* Wq = (const float*)d_in[1];
  const float* Wk = (const float*)d_in[2];
  const float* Wv = (const float*)d_in[3];
  float* out = (float*)d_out;

  char* ws = (char*)d_ws;
  u16* xb  = (u16*)(ws);                    // 16384*2048*2   = 67,108,864 B
  u16* wbt = (u16*)(ws + 67108864);         // 768*2048*2     =  3,145,728 B
  u16* qkv = (u16*)(ws + 70254592);         // 16384*768*2    = 25,165,824 B
  u16* vt  = (u16*)(ws + 95420416);         // 8*256*2048*2   =  8,388,608 B

  cast_x_kernel<<<16384, 256, 0, stream>>>(x, xb);
  cast_w_kernel<<<dim3(64, 8, 3), dim3(32, 8), 0, stream>>>(Wq, Wk, Wv, wbt);
  gemm_kernel<<<dim3(128, 6), 256, 0, stream>>>(xb, wbt, qkv);
  vtrans_kernel<<<dim3(64, 8, 8), dim3(32, 8), 0, stream>>>(qkv, vt);
  attn_kernel<<<dim3(64, 8), 256, 0, stream>>>(qkv, vt, out);
}

// Round 3
// 296.198 us; speedup vs baseline: 1.1473x; 1.0973x over previous
//
#include <hip/hip_runtime.h>
#include <hip/hip_bf16.h>

typedef unsigned short u16;
typedef unsigned int u32;
typedef __attribute__((ext_vector_type(8))) __bf16 bf16x8;
typedef __attribute__((ext_vector_type(4))) float f32x4;

// f32 -> bf16 round-to-nearest-even
__device__ __forceinline__ u16 f2bf(float f) {
  u32 u = __builtin_bit_cast(u32, f);
  return (u16)((u + 0x7fffu + ((u >> 16) & 1u)) >> 16);
}

// ---------------- cast x: fp32 -> bf16, 8 elems/thread ----------------
__global__ __launch_bounds__(256) void cast_x_kernel(const float* __restrict__ x,
                                                     u16* __restrict__ xb) {
  size_t i = ((size_t)blockIdx.x * 256 + threadIdx.x) * 8;
  float4 a = *(const float4*)(x + i);
  float4 b = *(const float4*)(x + i + 4);
  union { u16 h[8]; uint4 v; } o;
  o.h[0] = f2bf(a.x); o.h[1] = f2bf(a.y); o.h[2] = f2bf(a.z); o.h[3] = f2bf(a.w);
  o.h[4] = f2bf(b.x); o.h[5] = f2bf(b.y); o.h[6] = f2bf(b.z); o.h[7] = f2bf(b.w);
  *(uint4*)(xb + i) = o.v;
}

// ---------- cast + transpose W: [2048][256] f32 -> Wbt[768][2048] bf16 ----------
__global__ void cast_w_kernel(const float* __restrict__ Wq, const float* __restrict__ Wk,
                              const float* __restrict__ Wv, u16* __restrict__ wbt) {
  __shared__ float tile[32][33];
  int e0 = blockIdx.x * 32, d0 = blockIdx.y * 32, w = blockIdx.z;
  const float* W = (w == 0) ? Wq : ((w == 1) ? Wk : Wv);
  int x = threadIdx.x, y = threadIdx.y;
#pragma unroll
  for (int j = 0; j < 4; j++)
    tile[y + j * 8][x] = W[(size_t)(e0 + y + j * 8) * 256 + d0 + x];
  __syncthreads();
#pragma unroll
  for (int j = 0; j < 4; j++)
    wbt[(size_t)(w * 256 + d0 + y + j * 8) * 2048 + e0 + x] = f2bf(tile[x][y + j * 8]);
}

// ---------------- GEMM: qkv[16384][768] = xb[16384][2048] * Wbt^T ----------------
__global__ __launch_bounds__(256) void gemm_kernel(const u16* __restrict__ A,
                                                   const u16* __restrict__ Bt,
                                                   u16* __restrict__ C) {
  __shared__ __align__(16) u16 As[128 * 64];
  __shared__ __align__(16) u16 Bs[128 * 64];
  int tid = threadIdx.x;
  int w = tid >> 6, l = tid & 63;
  int lr = l & 15, lg = l >> 4;
  int row0 = blockIdx.x * 128, col0 = blockIdx.y * 128;
  int wr = w >> 1, wc = w & 1;

  f32x4 acc[4][4];
#pragma unroll
  for (int m = 0; m < 4; m++)
#pragma unroll
    for (int n = 0; n < 4; n++) acc[m][n] = (f32x4){0.f, 0.f, 0.f, 0.f};

  const u16* ga = A + (size_t)(row0 + w * 32 + (l >> 3)) * 2048 + (l & 7) * 8;
  const u16* gb = Bt + (size_t)(col0 + w * 32 + (l >> 3)) * 2048 + (l & 7) * 8;

  for (int kt = 0; kt < 2048; kt += 64) {
    __syncthreads();
#pragma unroll
    for (int j = 0; j < 4; j++) {
      __builtin_amdgcn_global_load_lds(
          (const __attribute__((address_space(1))) void*)(ga + kt + (size_t)j * 8 * 2048),
          (__attribute__((address_space(3))) void*)&As[w * 2048 + j * 512], 16, 0, 0);
      __builtin_amdgcn_global_load_lds(
          (const __attribute__((address_space(1))) void*)(gb + kt + (size_t)j * 8 * 2048),
          (__attribute__((address_space(3))) void*)&Bs[w * 2048 + j * 512], 16, 0, 0);
    }
    __syncthreads();
#pragma unroll
    for (int kk = 0; kk < 64; kk += 32) {
      bf16x8 af[4], bfr[4];
#pragma unroll
      for (int m = 0; m < 4; m++)
        af[m] = *(const bf16x8*)&As[(wr * 64 + m * 16 + lr) * 64 + kk + lg * 8];
#pragma unroll
      for (int n = 0; n < 4; n++)
        bfr[n] = *(const bf16x8*)&Bs[(wc * 64 + n * 16 + lr) * 64 + kk + lg * 8];
#pragma unroll
      for (int m = 0; m < 4; m++)
#pragma unroll
        for (int n = 0; n < 4; n++)
          acc[m][n] = __builtin_amdgcn_mfma_f32_16x16x32_bf16(af[m], bfr[n], acc[m][n], 0, 0, 0);
    }
  }
  int crow = row0 + wr * 64;
  int ccol = col0 + wc * 64 + lr;
#pragma unroll
  for (int m = 0; m < 4; m++)
#pragma unroll
    for (int n = 0; n < 4; n++)
#pragma unroll
      for (int i = 0; i < 4; i++)
        C[(size_t)(crow + m * 16 + lg * 4 + i) * 768 + ccol + n * 16] = f2bf(acc[m][n][i]);
}

// -------- K -> MFMA-fragment order: kfrag[b][t16][kc][lane][8] --------
// kfrag[((b*128+t16)*8+kc)*512 + l*8 + j] = K[b][t16*16+(l&15)][kc*32+(l>>4)*8+j]
// grid (64, 8), block 256; block handles kv rows [kvb*32, kvb*32+32)
__global__ __launch_bounds__(256) void kfrag_kernel(const u16* __restrict__ qkv,
                                                    u16* __restrict__ kfrag) {
  __shared__ __align__(16) u16 tile[32 * 264];  // stride 264 u16 = 528 B (16B-aligned)
  int t = threadIdx.x, kvb = blockIdx.x, b = blockIdx.y;
#pragma unroll
  for (int c = 0; c < 4; c++) {
    int m = c * 256 + t;
    int r = m >> 5, c16 = m & 31;
    bf16x8 v = *(const bf16x8*)(qkv + (size_t)(b * 2048 + kvb * 32 + r) * 768 + 256 + c16 * 8);
    *(bf16x8*)&tile[r * 264 + c16 * 8] = v;
  }
  __syncthreads();
#pragma unroll
  for (int c = 0; c < 4; c++) {
    int m = c * 256 + t;
    int t16l = m >> 9, kc = (m >> 6) & 7, l = m & 63;
    bf16x8 v = *(const bf16x8*)&tile[(t16l * 16 + (l & 15)) * 264 + kc * 32 + (l >> 4) * 8];
    *(bf16x8*)(kfrag + ((size_t)((b * 128 + kvb * 2 + t16l) * 8 + kc)) * 512 + l * 8) = v;
  }
}

// -------- V -> transposed MFMA-fragment order: vfrag[b][kvb][n][lane][8] --------
// vfrag[((b*64+kvb)*16+n)*512 + l*8 + j] = V[b][kvb*32+(l>>4)*8+j][n*16+(l&15)]
__global__ __launch_bounds__(256) void vfrag_kernel(const u16* __restrict__ qkv,
                                                    u16* __restrict__ vfrag) {
  __shared__ __align__(16) u16 tile[32 * 264];
  int t = threadIdx.x, kvb = blockIdx.x, b = blockIdx.y;
#pragma unroll
  for (int c = 0; c < 4; c++) {
    int m = c * 256 + t;
    int r = m >> 5, c16 = m & 31;
    bf16x8 v = *(const bf16x8*)(qkv + (size_t)(b * 2048 + kvb * 32 + r) * 768 + 512 + c16 * 8);
    *(bf16x8*)&tile[r * 264 + c16 * 8] = v;
  }
  __syncthreads();
#pragma unroll
  for (int c = 0; c < 4; c++) {
    int m = c * 256 + t;
    int n = m >> 6, l = m & 63;
    union { u16 h[8]; uint4 v; } o;
#pragma unroll
    for (int j = 0; j < 8; j++)
      o.h[j] = tile[((l >> 4) * 8 + j) * 264 + n * 16 + (l & 15)];
    *(uint4*)(vfrag + ((size_t)((b * 64 + kvb) * 16 + n)) * 512 + l * 8) = o.v;
  }
}

// ---------------- flash attention v3: frag-ordered K/V loads ----------------
// Same structure as v2 (KV-split waves + LSE merge); only K/V loads changed to
// contiguous 1KB fragment bursts from kfrag/vfrag.
__global__ __launch_bounds__(256, 2) void attn_kernel(const u16* __restrict__ qkv,
                                                      const u16* __restrict__ kfrag,
                                                      const u16* __restrict__ vfrag,
                                                      float* __restrict__ out) {
  __shared__ float facc[32][268];
  __shared__ float sm[4][32];
  __shared__ float sl[4][32];
  __shared__ __align__(16) u16 plds[4][32][40];

  int tid = threadIdx.x;
  int w = tid >> 6, l = tid & 63;
  int lr = l & 15, lg = l >> 4;
  int jt = 63 - blockIdx.x;
  int b = blockIdx.y;
  int q0 = jt * 32;

  const u16* qbase = qkv + (size_t)(b * 2048 + q0) * 768;
  bf16x8 qa[2][8];
#pragma unroll
  for (int qr = 0; qr < 2; qr++)
#pragma unroll
    for (int kc = 0; kc < 8; kc++)
      qa[qr][kc] = *(const bf16x8*)(qbase + (size_t)(qr * 16 + lr) * 768 + kc * 32 + lg * 8);

  f32x4 o[2][16];
#pragma unroll
  for (int qr = 0; qr < 2; qr++)
#pragma unroll
    for (int n = 0; n < 16; n++) o[qr][n] = (f32x4){0.f, 0.f, 0.f, 0.f};
  float mreg[2][4], ell[2][4];
#pragma unroll
  for (int qr = 0; qr < 2; qr++)
#pragma unroll
    for (int i = 0; i < 4; i++) { mreg[qr][i] = -__builtin_inff(); ell[qr][i] = 0.f; }

  int nkv = jt + 1;

  for (int jb = w; jb < nkv; jb += 4) {
    int kv0 = jb * 32;
    f32x4 s[2][2];
    s[0][0] = (f32x4){0.f,0.f,0.f,0.f}; s[0][1] = s[0][0];
    s[1][0] = s[0][0]; s[1][1] = s[0][0];
    // K frags: contiguous per (h,kc): 1KB burst
#pragma unroll
    for (int h = 0; h < 2; h++) {
      const u16* kfb = kfrag + ((size_t)((b * 128 + (kv0 >> 4) + h) * 8)) * 512 + l * 8;
      bf16x8 kfa[8];
#pragma unroll
      for (int kc = 0; kc < 8; kc++) kfa[kc] = *(const bf16x8*)(kfb + kc * 512);
#pragma unroll
      for (int kc = 0; kc < 8; kc++) {
        s[0][h] = __builtin_amdgcn_mfma_f32_16x16x32_bf16(qa[0][kc], kfa[kc], s[0][h], 0, 0, 0);
        s[1][h] = __builtin_amdgcn_mfma_f32_16x16x32_bf16(qa[1][kc], kfa[kc], s[1][h], 0, 0, 0);
      }
    }

    float sv[2][2][4];
    if (jb == jt) {
#pragma unroll
      for (int qr = 0; qr < 2; qr++)
#pragma unroll
        for (int h = 0; h < 2; h++)
#pragma unroll
          for (int i = 0; i < 4; i++) {
            int qrow = qr * 16 + lg * 4 + i;
            int krow = h * 16 + lr;
            sv[qr][h][i] = (krow <= qrow) ? s[qr][h][i] * (1.0f / 256.0f) : -__builtin_inff();
          }
    } else {
#pragma unroll
      for (int qr = 0; qr < 2; qr++)
#pragma unroll
        for (int h = 0; h < 2; h++)
#pragma unroll
          for (int i = 0; i < 4; i++)
            sv[qr][h][i] = s[qr][h][i] * (1.0f / 256.0f);
    }

    float sfv[2][4];
#pragma unroll
    for (int qr = 0; qr < 2; qr++)
#pragma unroll
      for (int i = 0; i < 4; i++) {
        float v0 = sv[qr][0][i], v1 = sv[qr][1][i];
        float mx = fmaxf(v0, v1);
        mx = fmaxf(mx, __shfl_xor(mx, 1));
        mx = fmaxf(mx, __shfl_xor(mx, 2));
        mx = fmaxf(mx, __shfl_xor(mx, 4));
        mx = fmaxf(mx, __shfl_xor(mx, 8));
        float mnew = fmaxf(mreg[qr][i], mx);
        float sf = __expf(mreg[qr][i] - mnew);
        float p0 = __expf(v0 - mnew);
        float p1 = __expf(v1 - mnew);
        plds[w][qr * 16 + lg * 4 + i][lr] = f2bf(p0);
        plds[w][qr * 16 + lg * 4 + i][16 + lr] = f2bf(p1);
        float ps = p0 + p1;
        ps += __shfl_xor(ps, 1);
        ps += __shfl_xor(ps, 2);
        ps += __shfl_xor(ps, 4);
        ps += __shfl_xor(ps, 8);
        ell[qr][i] = ell[qr][i] * sf + ps;
        mreg[qr][i] = mnew;
        sfv[qr][i] = sf;
      }

#pragma unroll
    for (int qr = 0; qr < 2; qr++)
#pragma unroll
      for (int n = 0; n < 16; n++) {
        f32x4 t = o[qr][n];
        t[0] *= sfv[qr][0]; t[1] *= sfv[qr][1]; t[2] *= sfv[qr][2]; t[3] *= sfv[qr][3];
        o[qr][n] = t;
      }

    bf16x8 pa0 = *(const bf16x8*)&plds[w][lr][lg * 8];
    bf16x8 pa1 = *(const bf16x8*)&plds[w][16 + lr][lg * 8];
    const u16* vfb = vfrag + ((size_t)((b * 64 + (kv0 >> 5)) * 16)) * 512 + l * 8;
#pragma unroll
    for (int n = 0; n < 16; n++) {
      bf16x8 vf = *(const bf16x8*)(vfb + (size_t)n * 512);
      o[0][n] = __builtin_amdgcn_mfma_f32_16x16x32_bf16(pa0, vf, o[0][n], 0, 0, 0);
      o[1][n] = __builtin_amdgcn_mfma_f32_16x16x32_bf16(pa1, vf, o[1][n], 0, 0, 0);
    }
  }

  if (lr == 0) {
#pragma unroll
    for (int qr = 0; qr < 2; qr++)
#pragma unroll
      for (int i = 0; i < 4; i++) {
        sm[w][qr * 16 + lg * 4 + i] = mreg[qr][i];
        sl[w][qr * 16 + lg * 4 + i] = ell[qr][i];
      }
  }
  __syncthreads();

  float alpha[2][4];
#pragma unroll
  for (int qr = 0; qr < 2; qr++)
#pragma unroll
    for (int i = 0; i < 4; i++) {
      int r = qr * 16 + lg * 4 + i;
      float M = fmaxf(fmaxf(sm[0][r], sm[1][r]), fmaxf(sm[2][r], sm[3][r]));
      alpha[qr][i] = __expf(mreg[qr][i] - M);
    }

#pragma unroll
  for (int ww = 0; ww < 4; ww++) {
    if (w == ww) {
#pragma unroll
      for (int qr = 0; qr < 2; qr++)
#pragma unroll
        for (int n = 0; n < 16; n++)
#pragma unroll
          for (int i = 0; i < 4; i++) {
            int r = qr * 16 + lg * 4 + i;
            float v = alpha[qr][i] * o[qr][n][i];
            if (ww == 0) facc[r][n * 16 + lr] = v;
            else facc[r][n * 16 + lr] += v;
          }
    }
    __syncthreads();
  }

  int r = tid >> 3, c0 = (tid & 7) * 32;
  float M = fmaxf(fmaxf(sm[0][r], sm[1][r]), fmaxf(sm[2][r], sm[3][r]));
  float denom = __expf(sm[0][r] - M) * sl[0][r] + __expf(sm[1][r] - M) * sl[1][r] +
                __expf(sm[2][r] - M) * sl[2][r] + __expf(sm[3][r] - M) * sl[3][r];
  float inv = 1.0f / denom;
  float* orow = out + (size_t)(b * 2048 + q0 + r) * 256;
#pragma unroll
  for (int j = 0; j < 8; j++) {
    float4 v = *(const float4*)&facc[r][c0 + j * 4];
    v.x *= inv; v.y *= inv; v.z *= inv; v.w *= inv;
    *(float4*)&orow[c0 + j * 4] = v;
  }
}

extern "C" void kernel_launch(void* const* d_in, const int* in_sizes, int n_in,
                              void* d_out, int out_size, void* d_ws, size_t ws_size,
                              hipStream_t stream) {
  (void)in_sizes; (void)n_in; (void)out_size; (void)ws_size;
  const float* x = (const float*)d_in[0];
  const float* Wq = (const float*)d_in[1];
  const float* Wk = (const float*)d_in[2];
  const float* Wv = (const float*)d_in[3];
  float* out = (float*)d_out;

  char* ws = (char*)d_ws;
  // Phase 1 layout (until gemm completes):
  u16* xb  = (u16*)(ws);                    // [0, 67,108,864)
  u16* wbt = (u16*)(ws + 67108864);         // [67,108,864, 70,254,592)
  u16* qkv = (u16*)(ws + 70254592);         // [70,254,592, 95,420,416)
  // Phase 2 (after gemm, xb dead): kfrag/vfrag alias onto xb region.
  u16* kfrag = (u16*)(ws);                  // 8*128*8*512*2 = 8,388,608 B
  u16* vfrag = (u16*)(ws + 8388608);        // 8*64*16*512*2 = 8,388,608 B

  cast_x_kernel<<<16384, 256, 0, stream>>>(x, xb);
  cast_w_kernel<<<dim3(64, 8, 3), dim3(32, 8), 0, stream>>>(Wq, Wk, Wv, wbt);
  gemm_kernel<<<dim3(128, 6), 256, 0, stream>>>(xb, wbt, qkv);
  kfrag_kernel<<<dim3(64, 8), 256, 0, stream>>>(qkv, kfrag);
  vfrag_kernel<<<dim3(64, 8), 256, 0, stream>>>(qkv, vfrag);
  attn_kernel<<<dim3(64, 8), 256, 0, stream>>>(qkv, kfrag, vfrag, out);
}

// Round 4
// 246.037 us; speedup vs baseline: 1.3812x; 1.2039x over previous
//
#include <hip/hip_runtime.h>
#include <hip/hip_bf16.h>

typedef unsigned short u16;
typedef unsigned int u32;
typedef __attribute__((ext_vector_type(8))) __bf16 bf16x8;
typedef __attribute__((ext_vector_type(4))) float f32x4;
typedef __attribute__((ext_vector_type(16))) float f32x16;

// f32 -> bf16 round-to-nearest-even
__device__ __forceinline__ u16 f2bf(float f) {
  u32 u = __builtin_bit_cast(u32, f);
  return (u16)((u + 0x7fffu + ((u >> 16) & 1u)) >> 16);
}
__device__ __forceinline__ float bf2f(u16 h) {
  u32 u = ((u32)h) << 16;
  return __builtin_bit_cast(float, u);
}

// ---------------- cast x: fp32 -> bf16, 8 elems/thread ----------------
__global__ __launch_bounds__(256) void cast_x_kernel(const float* __restrict__ x,
                                                     u16* __restrict__ xb) {
  size_t i = ((size_t)blockIdx.x * 256 + threadIdx.x) * 8;
  float4 a = *(const float4*)(x + i);
  float4 b = *(const float4*)(x + i + 4);
  union { u16 h[8]; uint4 v; } o;
  o.h[0] = f2bf(a.x); o.h[1] = f2bf(a.y); o.h[2] = f2bf(a.z); o.h[3] = f2bf(a.w);
  o.h[4] = f2bf(b.x); o.h[5] = f2bf(b.y); o.h[6] = f2bf(b.z); o.h[7] = f2bf(b.w);
  *(uint4*)(xb + i) = o.v;
}

// ---------- cast + transpose W: [2048][256] f32 -> Wbt[768][2048] bf16 ----------
__global__ void cast_w_kernel(const float* __restrict__ Wq, const float* __restrict__ Wk,
                              const float* __restrict__ Wv, u16* __restrict__ wbt) {
  __shared__ float tile[32][33];
  int e0 = blockIdx.x * 32, d0 = blockIdx.y * 32, w = blockIdx.z;
  const float* W = (w == 0) ? Wq : ((w == 1) ? Wk : Wv);
  int x = threadIdx.x, y = threadIdx.y;
#pragma unroll
  for (int j = 0; j < 4; j++)
    tile[y + j * 8][x] = W[(size_t)(e0 + y + j * 8) * 256 + d0 + x];
  __syncthreads();
#pragma unroll
  for (int j = 0; j < 4; j++)
    wbt[(size_t)(w * 256 + d0 + y + j * 8) * 2048 + e0 + x] = f2bf(tile[x][y + j * 8]);
}

// ---------------- GEMM: qkv[16384][768] = xb[16384][2048] * Wbt^T ----------------
__global__ __launch_bounds__(256) void gemm_kernel(const u16* __restrict__ A,
                                                   const u16* __restrict__ Bt,
                                                   u16* __restrict__ C) {
  __shared__ __align__(16) u16 As[128 * 64];
  __shared__ __align__(16) u16 Bs[128 * 64];
  int tid = threadIdx.x;
  int w = tid >> 6, l = tid & 63;
  int lr = l & 15, lg = l >> 4;
  int row0 = blockIdx.x * 128, col0 = blockIdx.y * 128;
  int wr = w >> 1, wc = w & 1;

  f32x4 acc[4][4];
#pragma unroll
  for (int m = 0; m < 4; m++)
#pragma unroll
    for (int n = 0; n < 4; n++) acc[m][n] = (f32x4){0.f, 0.f, 0.f, 0.f};

  const u16* ga = A + (size_t)(row0 + w * 32 + (l >> 3)) * 2048 + (l & 7) * 8;
  const u16* gb = Bt + (size_t)(col0 + w * 32 + (l >> 3)) * 2048 + (l & 7) * 8;

  for (int kt = 0; kt < 2048; kt += 64) {
    __syncthreads();
#pragma unroll
    for (int j = 0; j < 4; j++) {
      __builtin_amdgcn_global_load_lds(
          (const __attribute__((address_space(1))) void*)(ga + kt + (size_t)j * 8 * 2048),
          (__attribute__((address_space(3))) void*)&As[w * 2048 + j * 512], 16, 0, 0);
      __builtin_amdgcn_global_load_lds(
          (const __attribute__((address_space(1))) void*)(gb + kt + (size_t)j * 8 * 2048),
          (__attribute__((address_space(3))) void*)&Bs[w * 2048 + j * 512], 16, 0, 0);
    }
    __syncthreads();
#pragma unroll
    for (int kk = 0; kk < 64; kk += 32) {
      bf16x8 af[4], bfr[4];
#pragma unroll
      for (int m = 0; m < 4; m++)
        af[m] = *(const bf16x8*)&As[(wr * 64 + m * 16 + lr) * 64 + kk + lg * 8];
#pragma unroll
      for (int n = 0; n < 4; n++)
        bfr[n] = *(const bf16x8*)&Bs[(wc * 64 + n * 16 + lr) * 64 + kk + lg * 8];
#pragma unroll
      for (int m = 0; m < 4; m++)
#pragma unroll
        for (int n = 0; n < 4; n++)
          acc[m][n] = __builtin_amdgcn_mfma_f32_16x16x32_bf16(af[m], bfr[n], acc[m][n], 0, 0, 0);
    }
  }
  int crow = row0 + wr * 64;
  int ccol = col0 + wc * 64 + lr;
#pragma unroll
  for (int m = 0; m < 4; m++)
#pragma unroll
    for (int n = 0; n < 4; n++)
#pragma unroll
      for (int i = 0; i < 4; i++)
        C[(size_t)(crow + m * 16 + lg * 4 + i) * 768 + ccol + n * 16] = f2bf(acc[m][n][i]);
}

// -------- K -> swapped-A-frag order for mfma_32x32x16 --------
// kfrag[(((b*64+kvb)*16+t)*64+l)*8+j] = K[b][kvb*32+(l&31)][t*16+(l>>5)*8+j]
// grid (64, 8), block 256
__global__ __launch_bounds__(256) void kfrag_kernel(const u16* __restrict__ qkv,
                                                    u16* __restrict__ kfrag) {
  __shared__ __align__(16) u16 tile[32 * 264];
  int t = threadIdx.x, kvb = blockIdx.x, b = blockIdx.y;
#pragma unroll
  for (int c = 0; c < 4; c++) {
    int m = c * 256 + t;
    int r = m >> 5, c16 = m & 31;
    bf16x8 v = *(const bf16x8*)(qkv + (size_t)(b * 2048 + kvb * 32 + r) * 768 + 256 + c16 * 8);
    *(bf16x8*)&tile[r * 264 + c16 * 8] = v;
  }
  __syncthreads();
#pragma unroll
  for (int c = 0; c < 4; c++) {
    int m = c * 256 + t;
    int t16 = m >> 6, l = m & 63;
    bf16x8 v = *(const bf16x8*)&tile[(l & 31) * 264 + t16 * 16 + (l >> 5) * 8];
    *(bf16x8*)(kfrag + ((size_t)((b * 64 + kvb) * 16 + t16) * 64 + l) * 8) = v;
  }
}

// -------- V -> V^T A-frag order for PV mfma_32x32x16 --------
// vfrag[((((b*64+kvb)*2+ch)*8+dblk)*64+l)*8+j] = V[b][kvb*32+ch*16+(l>>5)*8+j][dblk*32+(l&31)]
__global__ __launch_bounds__(256) void vfrag_kernel(const u16* __restrict__ qkv,
                                                    u16* __restrict__ vfrag) {
  __shared__ __align__(16) u16 tile[32 * 264];
  int t = threadIdx.x, kvb = blockIdx.x, b = blockIdx.y;
#pragma unroll
  for (int c = 0; c < 4; c++) {
    int m = c * 256 + t;
    int r = m >> 5, c16 = m & 31;
    bf16x8 v = *(const bf16x8*)(qkv + (size_t)(b * 2048 + kvb * 32 + r) * 768 + 512 + c16 * 8);
    *(bf16x8*)&tile[r * 264 + c16 * 8] = v;
  }
  __syncthreads();
#pragma unroll
  for (int c = 0; c < 4; c++) {
    int m = c * 256 + t;
    int ch = m >> 9, dblk = (m >> 6) & 7, l = m & 63;
    union { u16 h[8]; uint4 v; } o;
#pragma unroll
    for (int j = 0; j < 8; j++)
      o.h[j] = tile[(ch * 16 + (l >> 5) * 8 + j) * 264 + dblk * 32 + (l & 31)];
    *(uint4*)(vfrag + ((size_t)(((b * 64 + kvb) * 2 + ch) * 8 + dblk) * 64 + l) * 8) = o.v;
  }
}

// ---------------- flash attention v4: swapped QK^T, in-lane softmax ----------------
// grid 512 (1D): b = bid&7 (batch-per-XCD), jti = bid>>3, jt triangle-paired.
// Block: 4 waves, 32 q rows shared; waves split KV blocks (32 wide) stride-4.
// Wave: S^T = mfma32x32x16(Kfrag, Qfrag); softmax in-lane (lane owns q-col l&31);
// P packed in-register -> PV B-frag; O^T acc 8x f32x16. Merge via facc + LSE.
__global__ __launch_bounds__(256, 2) void attn_kernel(const u16* __restrict__ qkv,
                                                      const u16* __restrict__ kfrag,
                                                      const u16* __restrict__ vfrag,
                                                      float* __restrict__ out) {
  __shared__ __align__(16) u16 qlds[16 * 512];  // Q B-frags, pre-scaled by 1/256
  __shared__ float facc[32][264];
  __shared__ float sm[4][32];
  __shared__ float sl[4][32];

  int tid = threadIdx.x;
  int w = tid >> 6, l = tid & 63;
  int ql = l & 31, hi = l >> 5;
  int bid = blockIdx.x;
  int b = bid & 7;
  int jti = bid >> 3;
  int jt = (jti < 32) ? (63 - jti) : (jti - 32);
  int q0 = jt * 32;

  // stage Q B-frags into LDS, scaled by 1/256 (exact exponent shift)
#pragma unroll
  for (int c = 0; c < 4; c++) {
    int m = c * 256 + tid;
    int t16 = m >> 6, ll = m & 63;
    const u16* src = qkv + (size_t)(b * 2048 + q0 + (ll & 31)) * 768 + t16 * 16 + (ll >> 5) * 8;
    union { u16 h[8]; bf16x8 v; } in, ov;
    in.v = *(const bf16x8*)src;
#pragma unroll
    for (int j = 0; j < 8; j++) ov.h[j] = f2bf(bf2f(in.h[j]) * (1.0f / 256.0f));
    *(bf16x8*)&qlds[(t16 * 64 + ll) * 8] = ov.v;
  }
  __syncthreads();

  f32x16 o[8];
#pragma unroll
  for (int d = 0; d < 8; d++)
#pragma unroll
    for (int r = 0; r < 16; r++) o[d][r] = 0.f;
  float mreg = -__builtin_inff(), ell = 0.f;

  for (int jb = w; jb <= jt; jb += 4) {
    // ---- QK^T (swapped): S^T[kv][q] ----
    f32x16 sA, sB;
#pragma unroll
    for (int r = 0; r < 16; r++) { sA[r] = 0.f; sB[r] = 0.f; }
    const u16* kb = kfrag + ((size_t)(b * 64 + jb) * 16 * 64 + l) * 8;
#pragma unroll
    for (int tg = 0; tg < 4; tg++) {
      bf16x8 k0 = *(const bf16x8*)(kb + (tg * 4 + 0) * 512);
      bf16x8 k1 = *(const bf16x8*)(kb + (tg * 4 + 1) * 512);
      bf16x8 k2 = *(const bf16x8*)(kb + (tg * 4 + 2) * 512);
      bf16x8 k3 = *(const bf16x8*)(kb + (tg * 4 + 3) * 512);
      bf16x8 q0f = *(const bf16x8*)&qlds[((tg * 4 + 0) * 64 + l) * 8];
      bf16x8 q1f = *(const bf16x8*)&qlds[((tg * 4 + 1) * 64 + l) * 8];
      bf16x8 q2f = *(const bf16x8*)&qlds[((tg * 4 + 2) * 64 + l) * 8];
      bf16x8 q3f = *(const bf16x8*)&qlds[((tg * 4 + 3) * 64 + l) * 8];
      sA = __builtin_amdgcn_mfma_f32_32x32x16_bf16(k0, q0f, sA, 0, 0, 0);
      sB = __builtin_amdgcn_mfma_f32_32x32x16_bf16(k1, q1f, sB, 0, 0, 0);
      sA = __builtin_amdgcn_mfma_f32_32x32x16_bf16(k2, q2f, sA, 0, 0, 0);
      sB = __builtin_amdgcn_mfma_f32_32x32x16_bf16(k3, q3f, sB, 0, 0, 0);
    }
    float s[16];
#pragma unroll
    for (int r = 0; r < 16; r++) s[r] = sA[r] + sB[r];

    // causal mask (diagonal tile only); lane's kv row for reg r:
    // kv = (r&3) + 8*(r>>2) + 4*hi
    if (jb == jt) {
#pragma unroll
      for (int r = 0; r < 16; r++) {
        int kv = (r & 3) + 8 * (r >> 2) + 4 * hi;
        if (kv > ql) s[r] = -__builtin_inff();
      }
    }

    // ---- in-lane online softmax (lane owns q-row ql; partner l^32 has other 16 kv) ----
    float mx = s[0];
#pragma unroll
    for (int r = 1; r < 16; r++) mx = fmaxf(mx, s[r]);
    mx = fmaxf(mx, __shfl_xor(mx, 32));
    float mnew = fmaxf(mreg, mx);
    float sf = __expf(mreg - mnew);
    float p[16];
    float ps = 0.f;
#pragma unroll
    for (int r = 0; r < 16; r++) { p[r] = __expf(s[r] - mnew); ps += p[r]; }
    ps += __shfl_xor(ps, 32);
    ell = ell * sf + ps;
    mreg = mnew;

    // ---- pack P to bf16 words; exchange halves; build PV B-frags ----
    u32 wv[8];
#pragma unroll
    for (int i = 0; i < 8; i++)
      wv[i] = (u32)f2bf(p[2 * i]) | ((u32)f2bf(p[2 * i + 1]) << 16);
    u32 sw[8];
#pragma unroll
    for (int i = 0; i < 8; i++) sw[i] = __shfl_xor(wv[i], 32);
    union { u32 u[4]; bf16x8 v; } B0, B1;
    B0.u[0] = hi ? sw[2] : wv[0];
    B0.u[1] = hi ? sw[3] : wv[1];
    B0.u[2] = hi ? wv[2] : sw[0];
    B0.u[3] = hi ? wv[3] : sw[1];
    B1.u[0] = hi ? sw[6] : wv[4];
    B1.u[1] = hi ? sw[7] : wv[5];
    B1.u[2] = hi ? wv[6] : sw[4];
    B1.u[3] = hi ? wv[7] : sw[5];

    // ---- rescale O^T by sf (lane-uniform scalar) ----
#pragma unroll
    for (int d = 0; d < 8; d++)
#pragma unroll
      for (int r = 0; r < 16; r++) o[d][r] *= sf;

    // ---- PV: O^T[d][q] += V^T[d][kv] * P^T[kv][q] ----
    const u16* vb = vfrag + ((size_t)(b * 64 + jb) * 16 * 64 + l) * 8;
#pragma unroll
    for (int d = 0; d < 8; d++) {
      bf16x8 v0 = *(const bf16x8*)(vb + d * 512);
      bf16x8 v1 = *(const bf16x8*)(vb + (8 + d) * 512);
      o[d] = __builtin_amdgcn_mfma_f32_32x32x16_bf16(v0, B0.v, o[d], 0, 0, 0);
      o[d] = __builtin_amdgcn_mfma_f32_32x32x16_bf16(v1, B1.v, o[d], 0, 0, 0);
    }
  }

  // ---- publish per-wave stats ----
  if (l < 32) { sm[w][l] = mreg; sl[w][l] = ell; }
  __syncthreads();

  float M = fmaxf(fmaxf(sm[0][ql], sm[1][ql]), fmaxf(sm[2][ql], sm[3][ql]));
  float alpha = __expf(mreg - M);

  // ---- sequential scaled accumulate into facc[q][d] ----
#pragma unroll
  for (int ww = 0; ww < 4; ww++) {
    if (w == ww) {
#pragma unroll
      for (int d = 0; d < 8; d++)
#pragma unroll
        for (int r = 0; r < 16; r++) {
          int dd = d * 32 + (r & 3) + 8 * (r >> 2) + 4 * hi;
          float v = alpha * o[d][r];
          if (ww == 0) facc[ql][dd] = v;
          else facc[ql][dd] += v;
        }
    }
    __syncthreads();
  }

  // ---- normalize + write out ----
  int r = tid >> 3, c0 = (tid & 7) * 32;
  float Mr = fmaxf(fmaxf(sm[0][r], sm[1][r]), fmaxf(sm[2][r], sm[3][r]));
  float denom = __expf(sm[0][r] - Mr) * sl[0][r] + __expf(sm[1][r] - Mr) * sl[1][r] +
                __expf(sm[2][r] - Mr) * sl[2][r] + __expf(sm[3][r] - Mr) * sl[3][r];
  float inv = 1.0f / denom;
  float* orow = out + (size_t)(b * 2048 + q0 + r) * 256;
#pragma unroll
  for (int j = 0; j < 8; j++) {
    float4 v = *(const float4*)&facc[r][c0 + j * 4];
    v.x *= inv; v.y *= inv; v.z *= inv; v.w *= inv;
    *(float4*)&orow[c0 + j * 4] = v;
  }
}

extern "C" void kernel_launch(void* const* d_in, const int* in_sizes, int n_in,
                              void* d_out, int out_size, void* d_ws, size_t ws_size,
                              hipStream_t stream) {
  (void)in_sizes; (void)n_in; (void)out_size; (void)ws_size;
  const float* x = (const float*)d_in[0];
  const float* Wq = (const float*)d_in[1];
  const float* Wk = (const float*)d_in[2];
  const float* Wv = (const float*)d_in[3];
  float* out = (float*)d_out;

  char* ws = (char*)d_ws;
  // Phase 1 layout (until gemm completes):
  u16* xb  = (u16*)(ws);                    // [0, 67,108,864)
  u16* wbt = (u16*)(ws + 67108864);         // [67,108,864, 70,254,592)
  u16* qkv = (u16*)(ws + 70254592);         // [70,254,592, 95,420,416)
  // Phase 2 (after gemm, xb dead): kfrag/vfrag alias onto xb region.
  u16* kfrag = (u16*)(ws);                  // 8*64*16*512*2 = 8,388,608 B
  u16* vfrag = (u16*)(ws + 8388608);        // 8*64*16*512*2 = 8,388,608 B

  cast_x_kernel<<<16384, 256, 0, stream>>>(x, xb);
  cast_w_kernel<<<dim3(64, 8, 3), dim3(32, 8), 0, stream>>>(Wq, Wk, Wv, wbt);
  gemm_kernel<<<dim3(128, 6), 256, 0, stream>>>(xb, wbt, qkv);
  kfrag_kernel<<<dim3(64, 8), 256, 0, stream>>>(qkv, kfrag);
  vfrag_kernel<<<dim3(64, 8), 256, 0, stream>>>(qkv, vfrag);
  attn_kernel<<<512, 256, 0, stream>>>(qkv, kfrag, vfrag, out);
}

// Round 6
// 212.519 us; speedup vs baseline: 1.5990x; 1.1577x over previous
//
#include <hip/hip_runtime.h>
#include <hip/hip_bf16.h>

typedef unsigned short u16;
typedef unsigned int u32;
typedef __attribute__((ext_vector_type(8))) __bf16 bf16x8;
typedef __attribute__((ext_vector_type(4))) float f32x4;
typedef __attribute__((ext_vector_type(16))) float f32x16;
typedef __attribute__((ext_vector_type(2))) unsigned u32x2;

// f32 -> bf16 round-to-nearest-even
__device__ __forceinline__ u16 f2bf(float f) {
  u32 u = __builtin_bit_cast(u32, f);
  return (u16)((u + 0x7fffu + ((u >> 16) & 1u)) >> 16);
}
__device__ __forceinline__ float bf2f(u16 h) {
  u32 u = ((u32)h) << 16;
  return __builtin_bit_cast(float, u);
}
// pack two floats to bf16x2 word
__device__ __forceinline__ u32 pk2(float lo, float hi) {
  union { __bf16 b[2]; u32 u; } r;
  r.b[0] = (__bf16)lo; r.b[1] = (__bf16)hi;
  return r.u;
}

// permlane32_swap: new_a[l<32]=a[l], new_a[l>=32]=b[l-32];
//                  new_b[l<32]=a[l+32], new_b[l>=32]=b[l].
// Use the intrinsic (proper SSA two-result semantics) — NOT raw asm with
// "+v","+v", which the register allocator may assign to ONE register when the
// inputs are the same value (v_permlane32_swap_b32 v5,v5 = garbage -> NaN).
__device__ __forceinline__ void pl32pair(u32& a, u32& b) {
#if __has_builtin(__builtin_amdgcn_permlane32_swap)
  u32x2 r = __builtin_amdgcn_permlane32_swap(a, b, 0, 0);
  a = r.x; b = r.y;
#else
  int hi = (int)((threadIdx.x & 63) >> 5);
  u32 as = __shfl_xor(a, 32), bs = __shfl_xor(b, 32);
  u32 na = hi ? bs : a;
  u32 nb = hi ? b : as;
  a = na; b = nb;
#endif
}
__device__ __forceinline__ float red_max32(float x) {
  u32 a = __builtin_bit_cast(u32, x), b = __builtin_bit_cast(u32, x);
  pl32pair(a, b);
  return fmaxf(__builtin_bit_cast(float, a), __builtin_bit_cast(float, b));
}
__device__ __forceinline__ float red_sum32(float x) {
  u32 a = __builtin_bit_cast(u32, x), b = __builtin_bit_cast(u32, x);
  pl32pair(a, b);
  return __builtin_bit_cast(float, a) + __builtin_bit_cast(float, b);
}

// ---------------- cast x: fp32 -> bf16, 8 elems/thread ----------------
__global__ __launch_bounds__(256) void cast_x_kernel(const float* __restrict__ x,
                                                     u16* __restrict__ xb) {
  size_t i = ((size_t)blockIdx.x * 256 + threadIdx.x) * 8;
  float4 a = *(const float4*)(x + i);
  float4 b = *(const float4*)(x + i + 4);
  union { u16 h[8]; uint4 v; } o;
  o.h[0] = f2bf(a.x); o.h[1] = f2bf(a.y); o.h[2] = f2bf(a.z); o.h[3] = f2bf(a.w);
  o.h[4] = f2bf(b.x); o.h[5] = f2bf(b.y); o.h[6] = f2bf(b.z); o.h[7] = f2bf(b.w);
  *(uint4*)(xb + i) = o.v;
}

// ---------- cast + transpose W: [2048][256] f32 -> Wbt[768][2048] bf16 ----------
__global__ void cast_w_kernel(const float* __restrict__ Wq, const float* __restrict__ Wk,
                              const float* __restrict__ Wv, u16* __restrict__ wbt) {
  __shared__ float tile[32][33];
  int e0 = blockIdx.x * 32, d0 = blockIdx.y * 32, w = blockIdx.z;
  const float* W = (w == 0) ? Wq : ((w == 1) ? Wk : Wv);
  int x = threadIdx.x, y = threadIdx.y;
#pragma unroll
  for (int j = 0; j < 4; j++)
    tile[y + j * 8][x] = W[(size_t)(e0 + y + j * 8) * 256 + d0 + x];
  __syncthreads();
#pragma unroll
  for (int j = 0; j < 4; j++)
    wbt[(size_t)(w * 256 + d0 + y + j * 8) * 2048 + e0 + x] = f2bf(tile[x][y + j * 8]);
}

// ---------------- GEMM: qkv[16384][768] = xb[16384][2048] * Wbt^T ----------------
__global__ __launch_bounds__(256) void gemm_kernel(const u16* __restrict__ A,
                                                   const u16* __restrict__ Bt,
                                                   u16* __restrict__ C) {
  __shared__ __align__(16) u16 As[128 * 64];
  __shared__ __align__(16) u16 Bs[128 * 64];
  int tid = threadIdx.x;
  int w = tid >> 6, l = tid & 63;
  int lr = l & 15, lg = l >> 4;
  int row0 = blockIdx.x * 128, col0 = blockIdx.y * 128;
  int wr = w >> 1, wc = w & 1;

  f32x4 acc[4][4];
#pragma unroll
  for (int m = 0; m < 4; m++)
#pragma unroll
    for (int n = 0; n < 4; n++) acc[m][n] = (f32x4){0.f, 0.f, 0.f, 0.f};

  const u16* ga = A + (size_t)(row0 + w * 32 + (l >> 3)) * 2048 + (l & 7) * 8;
  const u16* gb = Bt + (size_t)(col0 + w * 32 + (l >> 3)) * 2048 + (l & 7) * 8;

  for (int kt = 0; kt < 2048; kt += 64) {
    __syncthreads();
#pragma unroll
    for (int j = 0; j < 4; j++) {
      __builtin_amdgcn_global_load_lds(
          (const __attribute__((address_space(1))) void*)(ga + kt + (size_t)j * 8 * 2048),
          (__attribute__((address_space(3))) void*)&As[w * 2048 + j * 512], 16, 0, 0);
      __builtin_amdgcn_global_load_lds(
          (const __attribute__((address_space(1))) void*)(gb + kt + (size_t)j * 8 * 2048),
          (__attribute__((address_space(3))) void*)&Bs[w * 2048 + j * 512], 16, 0, 0);
    }
    __syncthreads();
#pragma unroll
    for (int kk = 0; kk < 64; kk += 32) {
      bf16x8 af[4], bfr[4];
#pragma unroll
      for (int m = 0; m < 4; m++)
        af[m] = *(const bf16x8*)&As[(wr * 64 + m * 16 + lr) * 64 + kk + lg * 8];
#pragma unroll
      for (int n = 0; n < 4; n++)
        bfr[n] = *(const bf16x8*)&Bs[(wc * 64 + n * 16 + lr) * 64 + kk + lg * 8];
#pragma unroll
      for (int m = 0; m < 4; m++)
#pragma unroll
        for (int n = 0; n < 4; n++)
          acc[m][n] = __builtin_amdgcn_mfma_f32_16x16x32_bf16(af[m], bfr[n], acc[m][n], 0, 0, 0);
    }
  }
  int crow = row0 + wr * 64;
  int ccol = col0 + wc * 64 + lr;
#pragma unroll
  for (int m = 0; m < 4; m++)
#pragma unroll
    for (int n = 0; n < 4; n++)
#pragma unroll
      for (int i = 0; i < 4; i++)
        C[(size_t)(crow + m * 16 + lg * 4 + i) * 768 + ccol + n * 16] = f2bf(acc[m][n][i]);
}

// -------- K -> swapped-A-frag order for mfma_32x32x16 --------
// kfrag[(((b*64+kvb)*16+t)*64+l)*8+j] = K[b][kvb*32+(l&31)][t*16+(l>>5)*8+j]
__global__ __launch_bounds__(256) void kfrag_kernel(const u16* __restrict__ qkv,
                                                    u16* __restrict__ kfrag) {
  __shared__ __align__(16) u16 tile[32 * 264];
  int t = threadIdx.x, kvb = blockIdx.x, b = blockIdx.y;
#pragma unroll
  for (int c = 0; c < 4; c++) {
    int m = c * 256 + t;
    int r = m >> 5, c16 = m & 31;
    bf16x8 v = *(const bf16x8*)(qkv + (size_t)(b * 2048 + kvb * 32 + r) * 768 + 256 + c16 * 8);
    *(bf16x8*)&tile[r * 264 + c16 * 8] = v;
  }
  __syncthreads();
#pragma unroll
  for (int c = 0; c < 4; c++) {
    int m = c * 256 + t;
    int t16 = m >> 6, l = m & 63;
    bf16x8 v = *(const bf16x8*)&tile[(l & 31) * 264 + t16 * 16 + (l >> 5) * 8];
    *(bf16x8*)(kfrag + ((size_t)((b * 64 + kvb) * 16 + t16) * 64 + l) * 8) = v;
  }
}

// -------- V -> V^T A-frag order for PV mfma_32x32x16 --------
// vfrag[((((b*64+kvb)*2+ch)*8+dblk)*64+l)*8+j] = V[b][kvb*32+ch*16+(l>>5)*8+j][dblk*32+(l&31)]
__global__ __launch_bounds__(256) void vfrag_kernel(const u16* __restrict__ qkv,
                                                    u16* __restrict__ vfrag) {
  __shared__ __align__(16) u16 tile[32 * 264];
  int t = threadIdx.x, kvb = blockIdx.x, b = blockIdx.y;
#pragma unroll
  for (int c = 0; c < 4; c++) {
    int m = c * 256 + t;
    int r = m >> 5, c16 = m & 31;
    bf16x8 v = *(const bf16x8*)(qkv + (size_t)(b * 2048 + kvb * 32 + r) * 768 + 512 + c16 * 8);
    *(bf16x8*)&tile[r * 264 + c16 * 8] = v;
  }
  __syncthreads();
#pragma unroll
  for (int c = 0; c < 4; c++) {
    int m = c * 256 + t;
    int ch = m >> 9, dblk = (m >> 6) & 7, l = m & 63;
    union { u16 h[8]; uint4 v; } o;
#pragma unroll
    for (int j = 0; j < 8; j++)
      o.h[j] = tile[(ch * 16 + (l >> 5) * 8 + j) * 264 + dblk * 32 + (l & 31)];
    *(uint4*)(vfrag + ((size_t)(((b * 64 + kvb) * 2 + ch) * 8 + dblk) * 64 + l) * 8) = o.v;
  }
}

// ---------------- flash attention v6 (v5 + intrinsic permlane fix) ----------------
// grid 256 (1 block/CU), 512 threads (8 waves). b = bid&7 (XCD affinity),
// p = bid>>3. Block processes tile pair jt = {63-p, p} sequentially -> every
// block has identical work (65 kv-block iterations) regardless of scheduling.
// Per tile: waves split kv blocks stride-8. Q in registers (pre-scaled 1/256),
// swapped QK^T (32x32x16), in-lane softmax with permlane32_swap reductions,
// defer-max (THR=8), P packed in-register -> PV B-frags via 4 permlane swaps.
// Merge: 8-phase sequential f32x4 accumulate into facc + LSE.
__global__ __launch_bounds__(512, 2) void attn_kernel(const u16* __restrict__ qkv,
                                                      const u16* __restrict__ kfrag,
                                                      const u16* __restrict__ vfrag,
                                                      float* __restrict__ out) {
  __shared__ float facc[32][264];
  __shared__ float sm[8][32];
  __shared__ float sl[8][32];

  int tid = threadIdx.x;
  int w = tid >> 6, l = tid & 63;
  int ql = l & 31, hi = l >> 5;
  int bid = blockIdx.x;
  int b = bid & 7;
  int p = bid >> 3;

  for (int tile = 0; tile < 2; tile++) {
    int jt = tile ? p : (63 - p);
    int q0 = jt * 32;

    // ---- Q B-frags in registers, pre-scaled by 1/256 (exact exp shift) ----
    const u16* qrow = qkv + (size_t)(b * 2048 + q0 + ql) * 768 + hi * 8;
    bf16x8 qf[16];
#pragma unroll
    for (int t = 0; t < 16; t++) {
      union { u16 h[8]; bf16x8 v; } in, ov;
      in.v = *(const bf16x8*)(qrow + t * 16);
#pragma unroll
      for (int j = 0; j < 8; j++) ov.h[j] = f2bf(bf2f(in.h[j]) * (1.0f / 256.0f));
      qf[t] = ov.v;
    }

    f32x16 o[8];
#pragma unroll
    for (int d = 0; d < 8; d++)
#pragma unroll
      for (int r = 0; r < 16; r++) o[d][r] = 0.f;
    float mreg = -__builtin_inff(), ell = 0.f;

    for (int jb = w; jb <= jt; jb += 8) {
      // ---- K frags: 16 contiguous 1KB bursts ----
      const u16* kb = kfrag + ((size_t)(b * 64 + jb) * 16 * 64 + l) * 8;
      bf16x8 kfa[16];
#pragma unroll
      for (int t = 0; t < 16; t++) kfa[t] = *(const bf16x8*)(kb + t * 512);

      f32x16 sA, sB;
#pragma unroll
      for (int r = 0; r < 16; r++) { sA[r] = 0.f; sB[r] = 0.f; }
#pragma unroll
      for (int t = 0; t < 16; t += 2) {
        sA = __builtin_amdgcn_mfma_f32_32x32x16_bf16(kfa[t], qf[t], sA, 0, 0, 0);
        sB = __builtin_amdgcn_mfma_f32_32x32x16_bf16(kfa[t + 1], qf[t + 1], sB, 0, 0, 0);
      }

      // ---- V frags issued early (independent of softmax) ----
      const u16* vb = vfrag + ((size_t)(b * 64 + jb) * 16 * 64 + l) * 8;
      bf16x8 vfa[16];
#pragma unroll
      for (int t = 0; t < 16; t++) vfa[t] = *(const bf16x8*)(vb + t * 512);

      float s[16];
#pragma unroll
      for (int r = 0; r < 16; r++) s[r] = sA[r] + sB[r];

      // causal mask (diagonal tile only); lane's kv for reg r: (r&3)+8*(r>>2)+4*hi
      if (jb == jt) {
#pragma unroll
        for (int r = 0; r < 16; r++) {
          int kv = (r & 3) + 8 * (r >> 2) + 4 * hi;
          if (kv > ql) s[r] = -__builtin_inff();
        }
      }

      // ---- in-lane online softmax; cross-half via permlane32_swap ----
      float mx = s[0];
#pragma unroll
      for (int r = 1; r < 16; r++) mx = fmaxf(mx, s[r]);
      mx = red_max32(mx);
      if (__any(mx > mreg + 8.f)) {  // defer-max: rescale only when max grows
        float mnew = fmaxf(mreg, mx);
        float sf = __expf(mreg - mnew);
        mreg = mnew;
        ell *= sf;
#pragma unroll
        for (int d = 0; d < 8; d++)
#pragma unroll
          for (int r = 0; r < 16; r++) o[d][r] *= sf;
      }
      float pr[16], ps = 0.f;
#pragma unroll
      for (int r = 0; r < 16; r++) { pr[r] = __expf(s[r] - mreg); ps += pr[r]; }
      ell += red_sum32(ps);

      // ---- pack P -> bf16 words; 4 permlane swaps build both B-frags ----
      u32 wv[8];
#pragma unroll
      for (int i = 0; i < 8; i++) wv[i] = pk2(pr[2 * i], pr[2 * i + 1]);
      pl32pair(wv[0], wv[2]); pl32pair(wv[1], wv[3]);
      pl32pair(wv[4], wv[6]); pl32pair(wv[5], wv[7]);
      union { u32 u[4]; bf16x8 v; } B0, B1;
      B0.u[0] = wv[0]; B0.u[1] = wv[1]; B0.u[2] = wv[2]; B0.u[3] = wv[3];
      B1.u[0] = wv[4]; B1.u[1] = wv[5]; B1.u[2] = wv[6]; B1.u[3] = wv[7];

      // ---- PV: O^T[d][q] += V^T[d][kv] * P^T[kv][q] ----
#pragma unroll
      for (int d = 0; d < 8; d++) {
        o[d] = __builtin_amdgcn_mfma_f32_32x32x16_bf16(vfa[d], B0.v, o[d], 0, 0, 0);
        o[d] = __builtin_amdgcn_mfma_f32_32x32x16_bf16(vfa[8 + d], B1.v, o[d], 0, 0, 0);
      }
    }

    // ---- merge across 8 waves ----
    __syncthreads();  // previous tile's facc/sm/sl readers done
    if (l < 32) { sm[w][l] = mreg; sl[w][l] = ell; }
    __syncthreads();

    float M = sm[0][ql];
#pragma unroll
    for (int ww = 1; ww < 8; ww++) M = fmaxf(M, sm[ww][ql]);
    float alpha = __expf(mreg - M);

#pragma unroll
    for (int ww = 0; ww < 8; ww++) {
      if (w == ww) {
#pragma unroll
        for (int d = 0; d < 8; d++)
#pragma unroll
          for (int rq = 0; rq < 4; rq++) {
            int base = d * 32 + 8 * rq + 4 * hi;
            f32x4 v;
#pragma unroll
            for (int i = 0; i < 4; i++) v[i] = alpha * o[d][rq * 4 + i];
            float* fp = &facc[ql][base];
            if (ww == 0) *(f32x4*)fp = v;
            else {
              f32x4 old = *(const f32x4*)fp;
              *(f32x4*)fp = old + v;
            }
          }
      }
      __syncthreads();
    }

    // ---- normalize + coalesced write ----
    int r = tid >> 4, lt = tid & 15;
    float Mr = sm[0][r];
#pragma unroll
    for (int ww = 1; ww < 8; ww++) Mr = fmaxf(Mr, sm[ww][r]);
    float denom = 0.f;
#pragma unroll
    for (int ww = 0; ww < 8; ww++) denom += __expf(sm[ww][r] - Mr) * sl[ww][r];
    float inv = 1.0f / denom;
    float* orow = out + (size_t)(b * 2048 + q0 + r) * 256;
#pragma unroll
    for (int j = 0; j < 4; j++) {
      int c = (lt + j * 16) * 4;
      f32x4 v = *(const f32x4*)&facc[r][c];
      v[0] *= inv; v[1] *= inv; v[2] *= inv; v[3] *= inv;
      *(f32x4*)&orow[c] = v;
    }
  }
}

extern "C" void kernel_launch(void* const* d_in, const int* in_sizes, int n_in,
                              void* d_out, int out_size, void* d_ws, size_t ws_size,
                              hipStream_t stream) {
  (void)in_sizes; (void)n_in; (void)out_size; (void)ws_size;
  const float* x = (const float*)d_in[0];
  const float* Wq = (const float*)d_in[1];
  const float* Wk = (const float*)d_in[2];
  const float* Wv = (const float*)d_in[3];
  float* out = (float*)d_out;

  char* ws = (char*)d_ws;
  // Phase 1 layout (until gemm completes):
  u16* xb  = (u16*)(ws);                    // [0, 67,108,864)
  u16* wbt = (u16*)(ws + 67108864);         // [67,108,864, 70,254,592)
  u16* qkv = (u16*)(ws + 70254592);         // [70,254,592, 95,420,416)
  // Phase 2 (after gemm, xb dead): kfrag/vfrag alias onto xb region.
  u16* kfrag = (u16*)(ws);                  // 8*64*16*512*2 = 8,388,608 B
  u16* vfrag = (u16*)(ws + 8388608);        // 8*64*16*512*2 = 8,388,608 B

  cast_x_kernel<<<16384, 256, 0, stream>>>(x, xb);
  cast_w_kernel<<<dim3(64, 8, 3), dim3(32, 8), 0, stream>>>(Wq, Wk, Wv, wbt);
  gemm_kernel<<<dim3(128, 6), 256, 0, stream>>>(xb, wbt, qkv);
  kfrag_kernel<<<dim3(64, 8), 256, 0, stream>>>(qkv, kfrag);
  vfrag_kernel<<<dim3(64, 8), 256, 0, stream>>>(qkv, vfrag);
  attn_kernel<<<256, 512, 0, stream>>>(qkv, kfrag, vfrag, out);
}

// Round 7
// 186.626 us; speedup vs baseline: 1.8209x; 1.1387x over previous
//
#include <hip/hip_runtime.h>
#include <hip/hip_bf16.h>

typedef unsigned short u16;
typedef unsigned int u32;
typedef __attribute__((ext_vector_type(8))) __bf16 bf16x8;
typedef __attribute__((ext_vector_type(4))) float f32x4;
typedef __attribute__((ext_vector_type(16))) float f32x16;
typedef __attribute__((ext_vector_type(2))) unsigned u32x2;

// f32 -> bf16 round-to-nearest-even
__device__ __forceinline__ u16 f2bf(float f) {
  u32 u = __builtin_bit_cast(u32, f);
  return (u16)((u + 0x7fffu + ((u >> 16) & 1u)) >> 16);
}
__device__ __forceinline__ float bf2f(u16 h) {
  u32 u = ((u32)h) << 16;
  return __builtin_bit_cast(float, u);
}
// pack two floats to bf16x2 word
__device__ __forceinline__ u32 pk2(float lo, float hi) {
  union { __bf16 b[2]; u32 u; } r;
  r.b[0] = (__bf16)lo; r.b[1] = (__bf16)hi;
  return r.u;
}

// permlane32_swap intrinsic wrapper (see round-5 NaN post-mortem: never raw asm
// with "+v","+v" on same-value operands).
__device__ __forceinline__ void pl32pair(u32& a, u32& b) {
#if __has_builtin(__builtin_amdgcn_permlane32_swap)
  u32x2 r = __builtin_amdgcn_permlane32_swap(a, b, 0, 0);
  a = r.x; b = r.y;
#else
  int hi = (int)((threadIdx.x & 63) >> 5);
  u32 as = __shfl_xor(a, 32), bs = __shfl_xor(b, 32);
  u32 na = hi ? bs : a;
  u32 nb = hi ? b : as;
  a = na; b = nb;
#endif
}
__device__ __forceinline__ float red_max32(float x) {
  u32 a = __builtin_bit_cast(u32, x), b = __builtin_bit_cast(u32, x);
  pl32pair(a, b);
  return fmaxf(__builtin_bit_cast(float, a), __builtin_bit_cast(float, b));
}
__device__ __forceinline__ float red_sum32(float x) {
  u32 a = __builtin_bit_cast(u32, x), b = __builtin_bit_cast(u32, x);
  pl32pair(a, b);
  return __builtin_bit_cast(float, a) + __builtin_bit_cast(float, b);
}

// ---------------- cast x: fp32 -> bf16, 8 elems/thread ----------------
__global__ __launch_bounds__(256) void cast_x_kernel(const float* __restrict__ x,
                                                     u16* __restrict__ xb) {
  size_t i = ((size_t)blockIdx.x * 256 + threadIdx.x) * 8;
  float4 a = *(const float4*)(x + i);
  float4 b = *(const float4*)(x + i + 4);
  union { u16 h[8]; uint4 v; } o;
  o.h[0] = f2bf(a.x); o.h[1] = f2bf(a.y); o.h[2] = f2bf(a.z); o.h[3] = f2bf(a.w);
  o.h[4] = f2bf(b.x); o.h[5] = f2bf(b.y); o.h[6] = f2bf(b.z); o.h[7] = f2bf(b.w);
  *(uint4*)(xb + i) = o.v;
}

// ---------- cast + transpose W: [2048][256] f32 -> Wbt[768][2048] bf16 ----------
__global__ void cast_w_kernel(const float* __restrict__ Wq, const float* __restrict__ Wk,
                              const float* __restrict__ Wv, u16* __restrict__ wbt) {
  __shared__ float tile[32][33];
  int e0 = blockIdx.x * 32, d0 = blockIdx.y * 32, w = blockIdx.z;
  const float* W = (w == 0) ? Wq : ((w == 1) ? Wk : Wv);
  int x = threadIdx.x, y = threadIdx.y;
#pragma unroll
  for (int j = 0; j < 4; j++)
    tile[y + j * 8][x] = W[(size_t)(e0 + y + j * 8) * 256 + d0 + x];
  __syncthreads();
#pragma unroll
  for (int j = 0; j < 4; j++)
    wbt[(size_t)(w * 256 + d0 + y + j * 8) * 2048 + e0 + x] = f2bf(tile[x][y + j * 8]);
}

// ------------- GEMM v2: phase-split, counted-vmcnt, 3-buffer rotation -------------
// qkv[16384][768] = xb[16384][2048] * Wbt[768][2048]^T   (both K-contiguous)
// BM=BN=256, BK=32, 512 threads (8 waves: 2M x 4N -> per-wave 128x64 output).
// LDS: 3 rotating buffers (As/Bs 16 KB each) = 96 KB. Tile t computes from
// buf t%3; its phases prefetch tile t+2 into buf (t+2)%3 (never active/next).
// Per tile: 2 phases x {ds_read; 2x global_load_lds; barrier; lgkmcnt(0);
// setprio(1); 16 MFMA; setprio(0); barrier}; ONE vmcnt(4) per tile (never 0).
// T2 swizzle: lds colbyte ^= (row&3)<<4, applied to READ addr + pre-swizzled
// GLOBAL source (gload_lds dest stays linear — rule 21).
__global__ __launch_bounds__(512, 2) void gemm_kernel(const u16* __restrict__ A,
                                                      const u16* __restrict__ Bt,
                                                      u16* __restrict__ C) {
  __shared__ __align__(16) u16 As[3][8192];
  __shared__ __align__(16) u16 Bs[3][8192];

  int tid = threadIdx.x;
  int w = tid >> 6, l = tid & 63;
  int lr = l & 15, lg = l >> 4;
  int wr = w >> 2, wc = w & 3;

  // XCD-chunked swizzle: 192 blocks, 24 per XCD, col-major virtual id so each
  // XCD's blocks share one B panel (1 MB, L2-resident).
  int bid = blockIdx.x;
  int vid = (bid & 7) * 24 + (bid >> 3);
  int colb = vid >> 6, rowb = vid & 63;
  int row0 = rowb * 256, col0 = colb * 256;

  // staging source coords (pre-swizzled): thread covers row c*128 + w*16 + (l>>2),
  // col elems (l&3)*8 ^ ((l>>2 & 3)*8), 16B contiguous.
  int srow = w * 16 + (l >> 2);
  int scol = ((l & 3) * 8) ^ (((l >> 2) & 3) * 8);
  const u16* ga = A + (size_t)(row0 + srow) * 2048 + scol;
  const u16* gb = Bt + (size_t)(col0 + srow) * 2048 + scol;

  f32x4 acc[8][4];
#pragma unroll
  for (int m = 0; m < 8; m++)
#pragma unroll
    for (int n = 0; n < 4; n++) acc[m][n] = (f32x4){0.f, 0.f, 0.f, 0.f};

  // swizzled LDS read column (u16 units)
  int rcol = (lg * 8) ^ ((lr & 3) * 8);

#define STAGE_A(ts, bi)                                                               \
  {                                                                                   \
    _Pragma("unroll") for (int c = 0; c < 2; c++)                                     \
        __builtin_amdgcn_global_load_lds(                                             \
            (const __attribute__((address_space(1))) void*)(ga + (size_t)c * 128 * 2048 + (ts) * 32), \
            (__attribute__((address_space(3))) void*)&As[bi][c * 4096 + w * 512], 16, 0, 0); \
  }
#define STAGE_B(ts, bi)                                                               \
  {                                                                                   \
    _Pragma("unroll") for (int c = 0; c < 2; c++)                                     \
        __builtin_amdgcn_global_load_lds(                                             \
            (const __attribute__((address_space(1))) void*)(gb + (size_t)c * 128 * 2048 + (ts) * 32), \
            (__attribute__((address_space(3))) void*)&Bs[bi][c * 4096 + w * 512], 16, 0, 0); \
  }

  // prologue: tiles 0,1 in flight; drain tile 0 (vmcnt(4) leaves tile 1 in flight)
  STAGE_A(0, 0); STAGE_B(0, 0);
  STAGE_A(1, 1); STAGE_B(1, 1);
  asm volatile("s_waitcnt vmcnt(4)" ::: "memory");
  __builtin_amdgcn_s_barrier();

  int bi = 0, bp = 2;  // active buffer, prefetch target ((t+2)%3)
  for (int t = 0; t < 64; t++) {
    int ts = (t + 2 <= 63) ? (t + 2) : 63;  // clamped prefetch (uniform vmcnt counts)
    const u16* asb = As[bi];
    const u16* bsb = Bs[bi];

    // ---- phase 0: B-frags (all 4) + A-frags m0-3; prefetch A(t+2) ----
    bf16x8 bfr[4], af[4];
#pragma unroll
    for (int n = 0; n < 4; n++)
      bfr[n] = *(const bf16x8*)&bsb[(wc * 64 + n * 16 + lr) * 32 + rcol];
#pragma unroll
    for (int m = 0; m < 4; m++)
      af[m] = *(const bf16x8*)&asb[(wr * 128 + m * 16 + lr) * 32 + rcol];
    STAGE_A(ts, bp);
    __builtin_amdgcn_s_barrier();
    asm volatile("s_waitcnt lgkmcnt(0)" ::: "memory");
    __builtin_amdgcn_sched_barrier(0);
    __builtin_amdgcn_s_setprio(1);
#pragma unroll
    for (int m = 0; m < 4; m++)
#pragma unroll
      for (int n = 0; n < 4; n++)
        acc[m][n] = __builtin_amdgcn_mfma_f32_16x16x32_bf16(af[m], bfr[n], acc[m][n], 0, 0, 0);
    __builtin_amdgcn_s_setprio(0);
    __builtin_amdgcn_s_barrier();

    // ---- phase 1: A-frags m4-7; prefetch B(t+2); counted vmcnt ----
    bf16x8 af2[4];
#pragma unroll
    for (int m = 0; m < 4; m++)
      af2[m] = *(const bf16x8*)&asb[(wr * 128 + (m + 4) * 16 + lr) * 32 + rcol];
    STAGE_B(ts, bp);
    asm volatile("s_waitcnt vmcnt(4)" ::: "memory");
    __builtin_amdgcn_s_barrier();
    asm volatile("s_waitcnt lgkmcnt(0)" ::: "memory");
    __builtin_amdgcn_sched_barrier(0);
    __builtin_amdgcn_s_setprio(1);
#pragma unroll
    for (int m = 0; m < 4; m++)
#pragma unroll
      for (int n = 0; n < 4; n++)
        acc[m + 4][n] = __builtin_amdgcn_mfma_f32_16x16x32_bf16(af2[m], bfr[n], acc[m + 4][n], 0, 0, 0);
    __builtin_amdgcn_s_setprio(0);
    __builtin_amdgcn_s_barrier();

    bi = (bi == 2) ? 0 : bi + 1;
    bp = (bp == 2) ? 0 : bp + 1;
  }
#undef STAGE_A
#undef STAGE_B

  // ---- C write: col = lane&15, row = (lane>>4)*4 + i (m89-verified) ----
  int crow = row0 + wr * 128;
  int ccol = col0 + wc * 64 + lr;
#pragma unroll
  for (int m = 0; m < 8; m++)
#pragma unroll
    for (int n = 0; n < 4; n++)
#pragma unroll
      for (int i = 0; i < 4; i++)
        C[(size_t)(crow + m * 16 + lg * 4 + i) * 768 + ccol + n * 16] = f2bf(acc[m][n][i]);
}

// -------- K -> swapped-A-frag order for mfma_32x32x16 --------
// kfrag[(((b*64+kvb)*16+t)*64+l)*8+j] = K[b][kvb*32+(l&31)][t*16+(l>>5)*8+j]
__global__ __launch_bounds__(256) void kfrag_kernel(const u16* __restrict__ qkv,
                                                    u16* __restrict__ kfrag) {
  __shared__ __align__(16) u16 tile[32 * 264];
  int t = threadIdx.x, kvb = blockIdx.x, b = blockIdx.y;
#pragma unroll
  for (int c = 0; c < 4; c++) {
    int m = c * 256 + t;
    int r = m >> 5, c16 = m & 31;
    bf16x8 v = *(const bf16x8*)(qkv + (size_t)(b * 2048 + kvb * 32 + r) * 768 + 256 + c16 * 8);
    *(bf16x8*)&tile[r * 264 + c16 * 8] = v;
  }
  __syncthreads();
#pragma unroll
  for (int c = 0; c < 4; c++) {
    int m = c * 256 + t;
    int t16 = m >> 6, l = m & 63;
    bf16x8 v = *(const bf16x8*)&tile[(l & 31) * 264 + t16 * 16 + (l >> 5) * 8];
    *(bf16x8*)(kfrag + ((size_t)((b * 64 + kvb) * 16 + t16) * 64 + l) * 8) = v;
  }
}

// -------- V -> V^T A-frag order for PV mfma_32x32x16 --------
// vfrag[((((b*64+kvb)*2+ch)*8+dblk)*64+l)*8+j] = V[b][kvb*32+ch*16+(l>>5)*8+j][dblk*32+(l&31)]
__global__ __launch_bounds__(256) void vfrag_kernel(const u16* __restrict__ qkv,
                                                    u16* __restrict__ vfrag) {
  __shared__ __align__(16) u16 tile[32 * 264];
  int t = threadIdx.x, kvb = blockIdx.x, b = blockIdx.y;
#pragma unroll
  for (int c = 0; c < 4; c++) {
    int m = c * 256 + t;
    int r = m >> 5, c16 = m & 31;
    bf16x8 v = *(const bf16x8*)(qkv + (size_t)(b * 2048 + kvb * 32 + r) * 768 + 512 + c16 * 8);
    *(bf16x8*)&tile[r * 264 + c16 * 8] = v;
  }
  __syncthreads();
#pragma unroll
  for (int c = 0; c < 4; c++) {
    int m = c * 256 + t;
    int ch = m >> 9, dblk = (m >> 6) & 7, l = m & 63;
    union { u16 h[8]; uint4 v; } o;
#pragma unroll
    for (int j = 0; j < 8; j++)
      o.h[j] = tile[(ch * 16 + (l >> 5) * 8 + j) * 264 + dblk * 32 + (l & 31)];
    *(uint4*)(vfrag + ((size_t)(((b * 64 + kvb) * 2 + ch) * 8 + dblk) * 64 + l) * 8) = o.v;
  }
}

// ---------------- flash attention v6 (passing; unchanged) ----------------
__global__ __launch_bounds__(512, 2) void attn_kernel(const u16* __restrict__ qkv,
                                                      const u16* __restrict__ kfrag,
                                                      const u16* __restrict__ vfrag,
                                                      float* __restrict__ out) {
  __shared__ float facc[32][264];
  __shared__ float sm[8][32];
  __shared__ float sl[8][32];

  int tid = threadIdx.x;
  int w = tid >> 6, l = tid & 63;
  int ql = l & 31, hi = l >> 5;
  int bid = blockIdx.x;
  int b = bid & 7;
  int p = bid >> 3;

  for (int tile = 0; tile < 2; tile++) {
    int jt = tile ? p : (63 - p);
    int q0 = jt * 32;

    const u16* qrow = qkv + (size_t)(b * 2048 + q0 + ql) * 768 + hi * 8;
    bf16x8 qf[16];
#pragma unroll
    for (int t = 0; t < 16; t++) {
      union { u16 h[8]; bf16x8 v; } in, ov;
      in.v = *(const bf16x8*)(qrow + t * 16);
#pragma unroll
      for (int j = 0; j < 8; j++) ov.h[j] = f2bf(bf2f(in.h[j]) * (1.0f / 256.0f));
      qf[t] = ov.v;
    }

    f32x16 o[8];
#pragma unroll
    for (int d = 0; d < 8; d++)
#pragma unroll
      for (int r = 0; r < 16; r++) o[d][r] = 0.f;
    float mreg = -__builtin_inff(), ell = 0.f;

    for (int jb = w; jb <= jt; jb += 8) {
      const u16* kb = kfrag + ((size_t)(b * 64 + jb) * 16 * 64 + l) * 8;
      bf16x8 kfa[16];
#pragma unroll
      for (int t = 0; t < 16; t++) kfa[t] = *(const bf16x8*)(kb + t * 512);

      f32x16 sA, sB;
#pragma unroll
      for (int r = 0; r < 16; r++) { sA[r] = 0.f; sB[r] = 0.f; }
#pragma unroll
      for (int t = 0; t < 16; t += 2) {
        sA = __builtin_amdgcn_mfma_f32_32x32x16_bf16(kfa[t], qf[t], sA, 0, 0, 0);
        sB = __builtin_amdgcn_mfma_f32_32x32x16_bf16(kfa[t + 1], qf[t + 1], sB, 0, 0, 0);
      }

      const u16* vb = vfrag + ((size_t)(b * 64 + jb) * 16 * 64 + l) * 8;
      bf16x8 vfa[16];
#pragma unroll
      for (int t = 0; t < 16; t++) vfa[t] = *(const bf16x8*)(vb + t * 512);

      float s[16];
#pragma unroll
      for (int r = 0; r < 16; r++) s[r] = sA[r] + sB[r];

      if (jb == jt) {
#pragma unroll
        for (int r = 0; r < 16; r++) {
          int kv = (r & 3) + 8 * (r >> 2) + 4 * hi;
          if (kv > ql) s[r] = -__builtin_inff();
        }
      }

      float mx = s[0];
#pragma unroll
      for (int r = 1; r < 16; r++) mx = fmaxf(mx, s[r]);
      mx = red_max32(mx);
      if (__any(mx > mreg + 8.f)) {
        float mnew = fmaxf(mreg, mx);
        float sf = __expf(mreg - mnew);
        mreg = mnew;
        ell *= sf;
#pragma unroll
        for (int d = 0; d < 8; d++)
#pragma unroll
          for (int r = 0; r < 16; r++) o[d][r] *= sf;
      }
      float pr[16], ps = 0.f;
#pragma unroll
      for (int r = 0; r < 16; r++) { pr[r] = __expf(s[r] - mreg); ps += pr[r]; }
      ell += red_sum32(ps);

      u32 wv[8];
#pragma unroll
      for (int i = 0; i < 8; i++) wv[i] = pk2(pr[2 * i], pr[2 * i + 1]);
      pl32pair(wv[0], wv[2]); pl32pair(wv[1], wv[3]);
      pl32pair(wv[4], wv[6]); pl32pair(wv[5], wv[7]);
      union { u32 u[4]; bf16x8 v; } B0, B1;
      B0.u[0] = wv[0]; B0.u[1] = wv[1]; B0.u[2] = wv[2]; B0.u[3] = wv[3];
      B1.u[0] = wv[4]; B1.u[1] = wv[5]; B1.u[2] = wv[6]; B1.u[3] = wv[7];

#pragma unroll
      for (int d = 0; d < 8; d++) {
        o[d] = __builtin_amdgcn_mfma_f32_32x32x16_bf16(vfa[d], B0.v, o[d], 0, 0, 0);
        o[d] = __builtin_amdgcn_mfma_f32_32x32x16_bf16(vfa[8 + d], B1.v, o[d], 0, 0, 0);
      }
    }

    __syncthreads();
    if (l < 32) { sm[w][l] = mreg; sl[w][l] = ell; }
    __syncthreads();

    float M = sm[0][ql];
#pragma unroll
    for (int ww = 1; ww < 8; ww++) M = fmaxf(M, sm[ww][ql]);
    float alpha = __expf(mreg - M);

#pragma unroll
    for (int ww = 0; ww < 8; ww++) {
      if (w == ww) {
#pragma unroll
        for (int d = 0; d < 8; d++)
#pragma unroll
          for (int rq = 0; rq < 4; rq++) {
            int base = d * 32 + 8 * rq + 4 * hi;
            f32x4 v;
#pragma unroll
            for (int i = 0; i < 4; i++) v[i] = alpha * o[d][rq * 4 + i];
            float* fp = &facc[ql][base];
            if (ww == 0) *(f32x4*)fp = v;
            else {
              f32x4 old = *(const f32x4*)fp;
              *(f32x4*)fp = old + v;
            }
          }
      }
      __syncthreads();
    }

    int r = tid >> 4, lt = tid & 15;
    float Mr = sm[0][r];
#pragma unroll
    for (int ww = 1; ww < 8; ww++) Mr = fmaxf(Mr, sm[ww][r]);
    float denom = 0.f;
#pragma unroll
    for (int ww = 0; ww < 8; ww++) denom += __expf(sm[ww][r] - Mr) * sl[ww][r];
    float inv = 1.0f / denom;
    float* orow = out + (size_t)(b * 2048 + q0 + r) * 256;
#pragma unroll
    for (int j = 0; j < 4; j++) {
      int c = (lt + j * 16) * 4;
      f32x4 v = *(const f32x4*)&facc[r][c];
      v[0] *= inv; v[1] *= inv; v[2] *= inv; v[3] *= inv;
      *(f32x4*)&orow[c] = v;
    }
  }
}

extern "C" void kernel_launch(void* const* d_in, const int* in_sizes, int n_in,
                              void* d_out, int out_size, void* d_ws, size_t ws_size,
                              hipStream_t stream) {
  (void)in_sizes; (void)n_in; (void)out_size; (void)ws_size;
  const float* x = (const float*)d_in[0];
  const float* Wq = (const float*)d_in[1];
  const float* Wk = (const float*)d_in[2];
  const float* Wv = (const float*)d_in[3];
  float* out = (float*)d_out;

  char* ws = (char*)d_ws;
  // Phase 1 layout (until gemm completes):
  u16* xb  = (u16*)(ws);                    // [0, 67,108,864)
  u16* wbt = (u16*)(ws + 67108864);         // [67,108,864, 70,254,592)
  u16* qkv = (u16*)(ws + 70254592);         // [70,254,592, 95,420,416)
  // Phase 2 (after gemm, xb dead): kfrag/vfrag alias onto xb region.
  u16* kfrag = (u16*)(ws);                  // 8*64*16*512*2 = 8,388,608 B
  u16* vfrag = (u16*)(ws + 8388608);        // 8*64*16*512*2 = 8,388,608 B

  cast_x_kernel<<<16384, 256, 0, stream>>>(x, xb);
  cast_w_kernel<<<dim3(64, 8, 3), dim3(32, 8), 0, stream>>>(Wq, Wk, Wv, wbt);
  gemm_kernel<<<192, 512, 0, stream>>>(xb, wbt, qkv);
  kfrag_kernel<<<dim3(64, 8), 256, 0, stream>>>(qkv, kfrag);
  vfrag_kernel<<<dim3(64, 8), 256, 0, stream>>>(qkv, vfrag);
  attn_kernel<<<256, 512, 0, stream>>>(qkv, kfrag, vfrag, out);
}